// Round 3
// baseline (1157.025 us; speedup 1.0000x reference)
//
#include <hip/hip_runtime.h>
#include <math.h>

#define B_ 16
#define N_ 1024
#define KNN 20
#define NPAIR (B_*N_)

// ---------- helpers ----------
__device__ __forceinline__ unsigned fkey(float f) {
  unsigned u = __float_as_uint(f);
  return (u & 0x80000000u) ? ~u : (u | 0x80000000u);
}
__device__ __forceinline__ float fkeyinv(unsigned u) {
  unsigned b = (u & 0x80000000u) ? (u ^ 0x80000000u) : ~u;
  return __uint_as_float(b);
}

// Branchless (cndmask-chain) insertion into a descending sorted top-20.
// Strict compare keeps earlier (lower-index) entries ahead on ties.
__device__ __forceinline__ void topk_insert(float (&pdl)[KNN], int (&idl)[KNN], float d, int j) {
  pdl[KNN-1] = d; idl[KNN-1] = j;
  #pragma unroll
  for (int i = KNN-1; i > 0; i--) {
    float a = pdl[i-1], bv = pdl[i];
    int ai = idl[i-1], bi = idl[i];
    bool sw = bv > a;
    pdl[i-1] = sw ? bv : a;   pdl[i] = sw ? a  : bv;
    idl[i-1] = sw ? bi : ai;  idl[i] = sw ? ai : bi;
  }
}

// ---------- 1) e2p of raw points ----------
__global__ void k_e2p1(const float* __restrict__ x, float* __restrict__ xp1) {
  int p = blockIdx.x * 256 + threadIdx.x;
  if (p >= NPAIR) return;
  float a0 = x[p*3+0], a1 = x[p*3+1], a2 = x[p*3+2];
  float n = sqrtf(a0*a0 + a1*a1 + a2*a2);
  n = fmaxf(n, 1e-15f);
  float th = tanhf(0.1f * n);
  float sc = th / (0.1f * n);
  float ny = fmaxf(th * 10.0f, 1e-15f);
  float mxn = (1.0f - 4e-3f) / 0.1f;
  if (ny > mxn) sc *= mxn / ny;
  xp1[p*3+0] = sc*a0; xp1[p*3+1] = sc*a1; xp1[p*3+2] = sc*a2;
}

// ---------- 2) knn on raw 3-d points: 4-way candidate split ----------
__global__ void __launch_bounds__(256) k_knn1_part(const float* __restrict__ x,
        float* __restrict__ pdpart, int* __restrict__ idxpart) {
  __shared__ float P[N_*3];
  __shared__ float XX[N_];
  int blk = blockIdx.x;
  int b = blk >> 4, rc = (blk >> 2) & 3, cc = blk & 3;
  const float* xb = x + b*N_*3;
  for (int e = threadIdx.x; e < N_*3; e += 256) P[e] = xb[e];
  __syncthreads();
  for (int j = threadIdx.x; j < N_; j += 256) {
    float q0 = P[j*3], q1 = P[j*3+1], q2 = P[j*3+2];
    XX[j] = q0*q0 + q1*q1 + q2*q2;
  }
  __syncthreads();
  int r = rc*256 + threadIdx.x;
  float q0 = P[r*3], q1 = P[r*3+1], q2 = P[r*3+2];
  float xxq = XX[r];
  float pdl[KNN]; int idl[KNN];
  #pragma unroll
  for (int i = 0; i < KNN; i++) { pdl[i] = -__builtin_inff(); idl[i] = 0; }
  int cbase = cc*256;
  for (int jj = 0; jj < 256; jj++) {
    int j = cbase + jj;
    float dot = q0*P[j*3] + q1*P[j*3+1] + q2*P[j*3+2];
    float d = 2.0f*dot - xxq - XX[j];
    if (d > pdl[KNN-1]) topk_insert(pdl, idl, d, j);
  }
  int p = b*N_ + r;
  float* pe = pdpart + (size_t)p*80 + cc*20;
  int* ie = idxpart + (size_t)p*80 + cc*20;
  #pragma unroll
  for (int i = 0; i < KNN; i++) { pe[i] = pdl[i]; ie[i] = idl[i]; }
}

// ---------- 3) conv1 fused ----------
__global__ void __launch_bounds__(256) k_conv1(const float* __restrict__ xp1, const int* __restrict__ idx1,
                        const float* __restrict__ w1, float* __restrict__ hmax1,
                        float* __restrict__ hmin1, double* __restrict__ stats1sh) {
  __shared__ float F[4][KNN][6];
  __shared__ float red[4][64][2];
  int g = threadIdx.x >> 6, lane = threadIdx.x & 63;
  float w[6];
  #pragma unroll
  for (int c = 0; c < 6; c++) w[c] = w1[lane*6 + c];
  float sum = 0.f, sumsq = 0.f;
  int pbase = blockIdx.x * 16;
  for (int it = 0; it < 4; ++it) {
    int p = pbase + it*4 + g;
    if (lane < KNN) {
      int nb = idx1[p*KNN + lane];
      int bb = p >> 10;
      const float* xc = xp1 + p*3;
      const float* ft = xp1 + (bb*N_ + nb)*3;
      float x0 = ft[0], x1 = ft[1], x2v = ft[2];
      float c0 = xc[0], c1 = xc[1], c2 = xc[2];
      float X2 = x0*x0 + x1*x1 + x2v*x2v;
      float Y2 = c0*c0 + c1*c1 + c2*c2;
      float XY = -(x0*c0 + x1*c1 + x2v*c2);
      float den = fmaxf(1.0f + 0.02f*XY + 1e-4f*X2*Y2, 1e-15f);
      float s1 = (1.0f + 0.02f*XY + 0.01f*Y2) / den;
      float s2 = (1.0f - 0.01f*X2) / den;
      F[g][lane][0] = s1*x0 - s2*c0;
      F[g][lane][1] = s1*x1 - s2*c1;
      F[g][lane][2] = s1*x2v - s2*c2;
      F[g][lane][3] = c0; F[g][lane][4] = c1; F[g][lane][5] = c2;
    }
    __syncthreads();
    float mx = -__builtin_inff(), mn = __builtin_inff();
    for (int k = 0; k < KNN; k++) {
      float h = 0.f;
      #pragma unroll
      for (int c = 0; c < 6; c++) h = fmaf(w[c], F[g][k][c], h);
      mx = fmaxf(mx, h); mn = fminf(mn, h);
      sum += h; sumsq += h*h;
    }
    hmax1[p*64 + lane] = mx;
    hmin1[p*64 + lane] = mn;
    __syncthreads();
  }
  red[g][lane][0] = sum; red[g][lane][1] = sumsq;
  __syncthreads();
  if (g == 0) {
    float s  = red[0][lane][0] + red[1][lane][0] + red[2][lane][0] + red[3][lane][0];
    float s2 = red[0][lane][1] + red[1][lane][1] + red[2][lane][1] + red[3][lane][1];
    double* dst = stats1sh + ((size_t)(blockIdx.x & 63)*64 + lane)*2;
    atomicAdd(dst, (double)s);
    atomicAdd(dst + 1, (double)s2);
  }
}

// ---------- BN stat reduce ----------
__global__ void k_bn_reduce(const double* __restrict__ sh, int nsh, int nch, double cnt,
                            const float* __restrict__ g, const float* __restrict__ bb,
                            float* __restrict__ scale, float* __restrict__ shift) {
  int o = blockIdx.x * blockDim.x + threadIdx.x;
  if (o >= nch) return;
  double s = 0.0, s2 = 0.0;
  for (int i = 0; i < nsh; i++) {
    s  += sh[((size_t)i*nch + o)*2];
    s2 += sh[((size_t)i*nch + o)*2 + 1];
  }
  double m = s / cnt;
  double v = s2 / cnt - m*m;
  float a = g[o] / sqrtf((float)v + 1e-5f);
  scale[o] = a;
  shift[o] = bb[o] - a * (float)m;
}

// ---------- 5) BN1 apply + relu + e2p of x1 + transposed copy + |x1|^2 ----------
__global__ void __launch_bounds__(256) k_bn1_apply(const float* __restrict__ hmax1, const float* __restrict__ hmin1,
                            const float* __restrict__ scale1, const float* __restrict__ shift1,
                            float* __restrict__ feat3, float* __restrict__ xp2,
                            float* __restrict__ x1T, float* __restrict__ xx1) {
  int p = blockIdx.x*4 + (threadIdx.x >> 6);
  int c = threadIdx.x & 63;
  float a = scale1[c], t = shift1[c];
  float h = (a >= 0.f) ? hmax1[p*64 + c] : hmin1[p*64 + c];
  float x1 = fmaxf(fmaf(a, h, t), 0.f);
  feat3[p*256 + c] = x1;
  int b = p >> 10, n = p & 1023;
  x1T[((size_t)(b*64 + c))*1024 + n] = x1;
  float n2 = x1*x1;
  #pragma unroll
  for (int off = 32; off > 0; off >>= 1) n2 += __shfl_xor(n2, off);
  if (c == 0) xx1[p] = n2;
  float n1 = fmaxf(sqrtf(n2), 1e-15f);
  float th = tanhf(0.1f * n1);
  float sc = th / (0.1f * n1);
  float ny = fmaxf(th * 10.0f, 1e-15f);
  float mxn = (1.0f - 4e-3f) / 0.1f;
  if (ny > mxn) sc *= mxn / ny;
  xp2[p*64 + c] = sc * x1;
}

// ---------- 6) knn2: GEMM-tiled distances + LDS selection ----------
// grid: b(16) x qchunk(8, 128 q) x cchunk(4, 256 cand) = 512 blocks, 256 thr.
// Per sub-tile (64 cand): stage As[64k][128q] (k-major) + Bs[64k][68] from x1T,
// register-tiled 8q x 4c GEMM, write D (overlaps As) with rotation swizzle,
// tid<128 lanes run guarded top-20 insert per query.
__global__ void __launch_bounds__(256) k_knn2g(const float* __restrict__ x1T,
        const float* __restrict__ xx1,
        float* __restrict__ pdpart, int* __restrict__ idxpart) {
  __shared__ __align__(16) float AsD[64*128];   // As (k-major) / D tile (reused)
  __shared__ __align__(16) float Bs[64*68];
  int tid = threadIdx.x;
  int blk = blockIdx.x;
  int b = blk >> 5, qc = (blk >> 2) & 7, cc = blk & 3;
  int qbase = qc*128, ccbase = cc*256;
  int tx = tid & 15, ty = tid >> 4;     // tx -> q-group, ty -> c-group
  int q0 = tx*8, c0 = ty*4;
  float pdl[KNN]; int idl[KNN];
  #pragma unroll
  for (int i = 0; i < KNN; i++) { pdl[i] = -__builtin_inff(); idl[i] = 0; }

  for (int st = 0; st < 4; ++st) {
    int cb0 = ccbase + st*64;
    // stage As: 64 k x 128 q = 2048 float4
    #pragma unroll
    for (int r = 0; r < 8; r++) {
      int e = tid + r*256;
      int k = e >> 5, qf = e & 31;
      float4 v = *((const float4*)(x1T + ((size_t)(b*64 + k))*1024 + qbase + qf*4));
      *((float4*)(AsD + k*128 + qf*4)) = v;
    }
    // stage Bs: 64 k x 64 c = 1024 float4
    #pragma unroll
    for (int r = 0; r < 4; r++) {
      int e = tid + r*256;
      int k = e >> 4, cf = e & 15;
      float4 v = *((const float4*)(x1T + ((size_t)(b*64 + k))*1024 + cb0 + cf*4));
      *((float4*)(Bs + k*68 + cf*4)) = v;
    }
    float4 xxc = *((const float4*)(xx1 + b*1024 + cb0 + c0));
    __syncthreads();
    // GEMM: acc[8][4]
    float acc[8][4];
    #pragma unroll
    for (int i = 0; i < 8; i++)
      #pragma unroll
      for (int j = 0; j < 4; j++) acc[i][j] = 0.f;
    #pragma unroll 4
    for (int k = 0; k < 64; k++) {
      float4 a0 = *((const float4*)(AsD + k*128 + q0));
      float4 a1 = *((const float4*)(AsD + k*128 + q0 + 4));
      float4 bv = *((const float4*)(Bs + k*68 + c0));
      float av[8] = {a0.x,a0.y,a0.z,a0.w,a1.x,a1.y,a1.z,a1.w};
      float bw[4] = {bv.x,bv.y,bv.z,bv.w};
      #pragma unroll
      for (int i = 0; i < 8; i++)
        #pragma unroll
        for (int j = 0; j < 4; j++) acc[i][j] = fmaf(av[i], bw[j], acc[i][j]);
    }
    __syncthreads();
    // write D (over As region) with rotation swizzle; fold -xxc (xxq const -> rank-invariant)
    float xxv[4] = {xxc.x, xxc.y, xxc.z, xxc.w};
    #pragma unroll
    for (int i = 0; i < 8; i++) {
      int q = q0 + i;
      #pragma unroll
      for (int j = 0; j < 4; j++) {
        int cl = c0 + j;
        AsD[q*64 + ((cl + q) & 63)] = 2.0f*acc[i][j] - xxv[j];
      }
    }
    __syncthreads();
    // selection: lanes 0..127 own one query each
    if (tid < 128) {
      int q = tid;
      for (int cl = 0; cl < 64; cl++) {
        float d = AsD[q*64 + ((cl + q) & 63)];
        if (d > pdl[KNN-1]) topk_insert(pdl, idl, d, cb0 + cl);
      }
    }
    __syncthreads();
  }
  if (tid < 128) {
    int p = b*N_ + qbase + tid;
    float* pe = pdpart + (size_t)p*80 + cc*20;
    int* ie = idxpart + (size_t)p*80 + cc*20;
    #pragma unroll
    for (int i = 0; i < KNN; i++) { pe[i] = pdl[i]; ie[i] = idl[i]; }
  }
}

// ---------- 7) merge 4 sorted top-20 chunks ----------
__global__ void k_knn2_merge(const float* __restrict__ pdpart, const int* __restrict__ idxpart,
                             int* __restrict__ idx2) {
  int p = blockIdx.x*256 + threadIdx.x;
  if (p >= NPAIR) return;
  const float* pe = pdpart + (size_t)p*80;
  const int* ie = idxpart + (size_t)p*80;
  int pos0 = 0, pos1 = 0, pos2 = 0, pos3 = 0;
  int* outp = idx2 + p*KNN;
  for (int t = 0; t < KNN; t++) {
    float best = -__builtin_inff(); int bi = 0x7FFFFFFF; int bc = 0;
    if (pos0 < KNN) { float pv = pe[pos0];      int iv = ie[pos0];      if (pv > best || (pv == best && iv < bi)) { best = pv; bi = iv; bc = 0; } }
    if (pos1 < KNN) { float pv = pe[20 + pos1]; int iv = ie[20 + pos1]; if (pv > best || (pv == best && iv < bi)) { best = pv; bi = iv; bc = 1; } }
    if (pos2 < KNN) { float pv = pe[40 + pos2]; int iv = ie[40 + pos2]; if (pv > best || (pv == best && iv < bi)) { best = pv; bi = iv; bc = 2; } }
    if (pos3 < KNN) { float pv = pe[60 + pos3]; int iv = ie[60 + pos3]; if (pv > best || (pv == best && iv < bi)) { best = pv; bi = iv; bc = 3; } }
    outp[t] = bi;
    if (bc == 0) pos0++; else if (bc == 1) pos1++; else if (bc == 2) pos2++; else pos3++;
  }
}

// ---------- 8) weight transposes ----------
__global__ void k_transpose(const float* __restrict__ w2, const float* __restrict__ w3,
                            float* __restrict__ wt2, float* __restrict__ wt3) {
  int i = blockIdx.x*256 + threadIdx.x;
  if (i < 192*128) { int o = i/128, c = i%128; wt2[c*192 + o] = w2[i]; }
  if (i < 1024*256) { int o = i/256, c = i%256; wt3[c*1024 + o] = w3[i]; }
}

// ---------- 9) conv2 fused: mobius A-tile + GEMM (W staged in LDS) + stats + max/min ----------
__global__ void __launch_bounds__(256) k_conv2(const float* __restrict__ xp2,
    const int* __restrict__ idx2, const float* __restrict__ wt2,
    float* __restrict__ hmax2, float* __restrict__ hmin2, double* __restrict__ stats2sh) {
  __shared__ __align__(16) float A[80*132];
  __shared__ __align__(16) float Ws[16*192];
  __shared__ __align__(16) float xcs[256];
  __shared__ float s1s[80], s2s[80];
  __shared__ int nbr[80];
  int tid = threadIdx.x;
  int ty = tid >> 4, tx = tid & 15;
  int p0 = blockIdx.x * 4;
  int b = p0 >> 10;
  {
    int g = tid >> 6, c = tid & 63;
    xcs[tid] = xp2[(size_t)(p0 + g)*64 + c];
  }
  if (tid < 80) nbr[tid] = idx2[p0*KNN + tid];
  __syncthreads();
  // phase1: A[r][0:64] = neighbor feat, A[r][64:128] = xc
  for (int e = tid; e < 80*32; e += 256) {
    int r = e >> 5, qq = e & 31;
    if (qq < 16) {
      float4 v = *((const float4*)(xp2 + (size_t)(b*N_ + nbr[r])*64) + qq);
      *((float4*)(A + r*132) + qq) = v;
    } else {
      int g = r / 20;
      *((float4*)(A + r*132 + 64) + (qq - 16)) = *((const float4*)(xcs + g*64) + (qq - 16));
    }
  }
  __syncthreads();
  // phase2: per-row mobius scalars
  if (tid < 80) {
    const float* Ar = A + tid*132;
    float X2 = 0.f, XY = 0.f, Y2 = 0.f;
    for (int c2 = 0; c2 < 64; c2++) {
      float f = Ar[c2], xcv = Ar[64 + c2];
      X2 = fmaf(f, f, X2); XY = fmaf(-f, xcv, XY); Y2 = fmaf(xcv, xcv, Y2);
    }
    float den = fmaxf(1.0f + 0.02f*XY + 1e-4f*X2*Y2, 1e-15f);
    s1s[tid] = (1.0f + 0.02f*XY + 0.01f*Y2) / den;
    s2s[tid] = (1.0f - 0.01f*X2) / den;
  }
  __syncthreads();
  // phase3: A[r][0:64] = s1*feat - s2*xc
  for (int e = tid; e < 80*16; e += 256) {
    int r = e >> 4, qq = e & 15;
    float4 f = *((float4*)(A + r*132) + qq);
    float4 c4v = *((const float4*)(A + r*132 + 64) + qq);
    float s1 = s1s[r], s2 = s2s[r];
    f.x = s1*f.x - s2*c4v.x; f.y = s1*f.y - s2*c4v.y;
    f.z = s1*f.z - s2*c4v.z; f.w = s1*f.w - s2*c4v.w;
    *((float4*)(A + r*132) + qq) = f;
  }
  // GEMM: 80x192, K=128, W streamed through LDS in 16-kc chunks
  float acc[5][12];
  #pragma unroll
  for (int i = 0; i < 5; i++)
    #pragma unroll
    for (int j = 0; j < 12; j++) acc[i][j] = 0.f;
  const float4* wtv = (const float4*)wt2;
  for (int kb = 0; kb < 128; kb += 16) {
    __syncthreads();
    #pragma unroll
    for (int r = 0; r < 3; r++) {
      int e = tid + r*256;
      ((float4*)Ws)[e] = wtv[kb*48 + e];
    }
    __syncthreads();
    #pragma unroll
    for (int kc2 = 0; kc2 < 16; kc2++) {
      int kc = kb + kc2;
      float4 w0 = *((const float4*)(Ws + kc2*192 + 4*tx));
      float4 w1 = *((const float4*)(Ws + kc2*192 + 64 + 4*tx));
      float4 w2 = *((const float4*)(Ws + kc2*192 + 128 + 4*tx));
      float wv[12] = {w0.x,w0.y,w0.z,w0.w, w1.x,w1.y,w1.z,w1.w, w2.x,w2.y,w2.z,w2.w};
      float ar[5];
      #pragma unroll
      for (int i = 0; i < 5; i++) ar[i] = A[(ty + 16*i)*132 + kc];
      #pragma unroll
      for (int i = 0; i < 5; i++) {
        #pragma unroll
        for (int j = 0; j < 12; j++) acc[i][j] = fmaf(ar[i], wv[j], acc[i][j]);
      }
    }
  }
  __syncthreads();
  // stats: per-channel sum/sumsq -> shadow atomics
  float* redbuf = A;
  #pragma unroll
  for (int cc2 = 0; cc2 < 12; cc2++) {
    float s = 0.f, s2 = 0.f;
    #pragma unroll
    for (int i = 0; i < 5; i++) { float h = acc[i][cc2]; s += h; s2 += h*h; }
    redbuf[tid*25 + cc2*2] = s; redbuf[tid*25 + cc2*2 + 1] = s2;
  }
  __syncthreads();
  if (ty == 0) {
    for (int cc2 = 0; cc2 < 12; cc2++) {
      float s = 0.f, s2 = 0.f;
      for (int yy = 0; yy < 16; yy++) {
        s  += redbuf[(yy*16 + tx)*25 + cc2*2];
        s2 += redbuf[(yy*16 + tx)*25 + cc2*2 + 1];
      }
      int o = (cc2 >> 2)*64 + 4*tx + (cc2 & 3);
      double* dst = stats2sh + ((size_t)(blockIdx.x & 63)*192 + o)*2;
      atomicAdd(dst, (double)s); atomicAdd(dst + 1, (double)s2);
    }
  }
  // max/min over k per (pair, channel); stride 17 pad to kill 4-way conflicts
  float* mmb = A;
  #pragma unroll
  for (int cc2 = 0; cc2 < 12; cc2++) {
    __syncthreads();
    #pragma unroll
    for (int i = 0; i < 5; i++) mmb[(ty + 16*i)*17 + tx] = acc[i][cc2];
    __syncthreads();
    if (tid < 64) {
      int g = tid >> 4, xx2 = tid & 15;
      float mx = -__builtin_inff(), mn = __builtin_inff();
      for (int kk = 0; kk < KNN; kk++) {
        float h = mmb[(g*20 + kk)*17 + xx2];
        mx = fmaxf(mx, h); mn = fminf(mn, h);
      }
      int o = (cc2 >> 2)*64 + 4*xx2 + (cc2 & 3);
      hmax2[(size_t)(p0 + g)*192 + o] = mx;
      hmin2[(size_t)(p0 + g)*192 + o] = mn;
    }
  }
}

// ---------- 10) BN2 apply ----------
__global__ void k_bn2_apply(const float* __restrict__ hmax2, const float* __restrict__ hmin2,
                            const float* __restrict__ scale2, const float* __restrict__ shift2,
                            float* __restrict__ feat3) {
  int e = blockIdx.x*256 + threadIdx.x;
  if (e >= NPAIR*192) return;
  int p = e / 192, o = e - p*192;
  float a = scale2[o], t = shift2[o];
  float h = (a >= 0.f) ? hmax2[e] : hmin2[e];
  feat3[(size_t)p*256 + 64 + o] = fmaxf(fmaf(a, h, t), 0.f);
}

// ---------- 11) conv3 GEMM + stats + max/min over n ----------
__global__ void __launch_bounds__(256) k_conv3(const float* __restrict__ feat3,
   const float* __restrict__ wt3, double* __restrict__ stats3,
   unsigned* __restrict__ hmax3u, unsigned* __restrict__ hmin3u) {
  __shared__ __align__(16) float A[64*68];
  __shared__ float buf[256*16];
  int tid = threadIdx.x, ty = tid >> 4, tx = tid & 15;
  int mt = blockIdx.x >> 2, cb = blockIdx.x & 3;
  int rowbase = mt*64;
  int b = rowbase >> 10;
  float acc[4][16];
  #pragma unroll
  for (int i = 0; i < 4; i++)
    #pragma unroll
    for (int j = 0; j < 16; j++) acc[i][j] = 0.f;
  for (int ch = 0; ch < 4; ch++) {
    int kb = ch*64;
    __syncthreads();
    for (int e = tid; e < 64*16; e += 256) {
      int rr = e >> 4, c4 = e & 15;
      *((float4*)(A + rr*68) + c4) = *((const float4*)(feat3 + (size_t)(rowbase + rr)*256 + kb) + c4);
    }
    __syncthreads();
    for (int kc = 0; kc < 64; kc++) {
      int kglob = kb + kc;
      float4 w[4];
      #pragma unroll
      for (int j = 0; j < 4; j++)
        w[j] = *((const float4*)(wt3 + (size_t)kglob*1024 + cb*256 + j*64 + 4*tx));
      float a[4];
      #pragma unroll
      for (int i = 0; i < 4; i++) a[i] = A[(ty + 16*i)*68 + kc];
      #pragma unroll
      for (int i = 0; i < 4; i++) {
        #pragma unroll
        for (int j = 0; j < 4; j++) {
          acc[i][j*4+0] = fmaf(a[i], w[j].x, acc[i][j*4+0]);
          acc[i][j*4+1] = fmaf(a[i], w[j].y, acc[i][j*4+1]);
          acc[i][j*4+2] = fmaf(a[i], w[j].z, acc[i][j*4+2]);
          acc[i][j*4+3] = fmaf(a[i], w[j].w, acc[i][j*4+3]);
        }
      }
    }
  }
  #pragma unroll
  for (int j = 0; j < 4; j++) {
    __syncthreads();
    #pragma unroll
    for (int q = 0; q < 4; q++) {
      float s = 0.f, s2 = 0.f, mx = -__builtin_inff(), mn = __builtin_inff();
      #pragma unroll
      for (int i = 0; i < 4; i++) {
        float h = acc[i][j*4+q];
        s += h; s2 += h*h; mx = fmaxf(mx, h); mn = fminf(mn, h);
      }
      float* bp = buf + tid*16 + q*4;
      bp[0] = s; bp[1] = s2; bp[2] = mx; bp[3] = mn;
    }
    __syncthreads();
    if (ty == 0) {
      #pragma unroll
      for (int q = 0; q < 4; q++) {
        float s = 0.f, s2 = 0.f, mx = -__builtin_inff(), mn = __builtin_inff();
        for (int yy = 0; yy < 16; yy++) {
          const float* bp = buf + (yy*16 + tx)*16 + q*4;
          s += bp[0]; s2 += bp[1]; mx = fmaxf(mx, bp[2]); mn = fminf(mn, bp[3]);
        }
        int o = cb*256 + j*64 + 4*tx + q;
        atomicAdd(stats3 + (size_t)o*2, (double)s);
        atomicAdd(stats3 + (size_t)o*2 + 1, (double)s2);
        atomicMax(hmax3u + b*1024 + o, fkey(mx));
        atomicMin(hmin3u + b*1024 + o, fkey(mn));
      }
    }
  }
}

// ---------- 12) head ----------
__device__ float blk_reduce(float v, float* red, int tid) {
  red[tid] = v; __syncthreads();
  for (int st = 128; st > 0; st >>= 1) {
    if (tid < st) red[tid] += red[tid + st];
    __syncthreads();
  }
  float r = red[0]; __syncthreads();
  return r;
}

__global__ void __launch_bounds__(256) k_head(const unsigned* __restrict__ hmax3u, const unsigned* __restrict__ hmin3u,
    const float* __restrict__ scale3, const float* __restrict__ shift3,
    const float* __restrict__ fc1w, const float* __restrict__ fc1b,
    const float* __restrict__ ln1g, const float* __restrict__ ln1b,
    const float* __restrict__ fc2w, const float* __restrict__ fc2b,
    const float* __restrict__ ln2g, const float* __restrict__ ln2b,
    const float* __restrict__ outw, const float* __restrict__ outb,
    float* __restrict__ out) {
  __shared__ __align__(16) float V[1024];
  __shared__ __align__(16) float H1[512];
  __shared__ __align__(16) float H2[256];
  __shared__ float red[256];
  int b = blockIdx.x, tid = threadIdx.x;
  for (int o = tid; o < 1024; o += 256) {
    float a = scale3[o];
    unsigned u = (a >= 0.f) ? hmax3u[b*1024 + o] : hmin3u[b*1024 + o];
    float h = fkeyinv(u);
    V[o] = fmaxf(fmaf(a, h, shift3[o]), 0.f);
  }
  __syncthreads();
  float h1v[2];
  #pragma unroll
  for (int ii = 0; ii < 2; ii++) {
    int o = tid + ii*256;
    const float4* wr = (const float4*)(fc1w + (size_t)o*1024);
    float s = 0.f;
    for (int c4 = 0; c4 < 256; c4++) {
      float4 w = wr[c4]; float4 vv = ((const float4*)V)[c4];
      s = fmaf(w.x, vv.x, s); s = fmaf(w.y, vv.y, s);
      s = fmaf(w.z, vv.z, s); s = fmaf(w.w, vv.w, s);
    }
    h1v[ii] = s + fc1b[o];
  }
  float s = h1v[0] + h1v[1];
  float s2 = h1v[0]*h1v[0] + h1v[1]*h1v[1];
  s = blk_reduce(s, red, tid);
  s2 = blk_reduce(s2, red, tid);
  float m = s / 512.f;
  float var = s2 / 512.f - m*m;
  float inv = 1.0f / sqrtf(var + 1e-5f);
  #pragma unroll
  for (int ii = 0; ii < 2; ii++) {
    int o = tid + ii*256;
    H1[o] = fmaxf((h1v[ii] - m)*inv*ln1g[o] + ln1b[o], 0.f);
  }
  __syncthreads();
  float h2v;
  {
    const float4* wr = (const float4*)(fc2w + (size_t)tid*512);
    float t = 0.f;
    for (int c4 = 0; c4 < 128; c4++) {
      float4 w = wr[c4]; float4 vv = ((const float4*)H1)[c4];
      t = fmaf(w.x, vv.x, t); t = fmaf(w.y, vv.y, t);
      t = fmaf(w.z, vv.z, t); t = fmaf(w.w, vv.w, t);
    }
    h2v = t + fc2b[tid];
  }
  float ss = blk_reduce(h2v, red, tid);
  float ss2 = blk_reduce(h2v*h2v, red, tid);
  float m2 = ss / 256.f;
  float var2 = ss2 / 256.f - m2*m2;
  float inv2 = 1.0f / sqrtf(var2 + 1e-5f);
  H2[tid] = fmaxf((h2v - m2)*inv2*ln2g[tid] + ln2b[tid], 0.f);
  __syncthreads();
  if (tid < 40) {
    const float4* wr = (const float4*)(outw + (size_t)tid*256);
    float t = 0.f;
    for (int c4 = 0; c4 < 64; c4++) {
      float4 w = wr[c4]; float4 vv = ((const float4*)H2)[c4];
      t = fmaf(w.x, vv.x, t); t = fmaf(w.y, vv.y, t);
      t = fmaf(w.z, vv.z, t); t = fmaf(w.w, vv.w, t);
    }
    red[tid] = t + outb[tid];
  }
  __syncthreads();
  if (tid == 0) {
    float mx = -__builtin_inff();
    for (int i2 = 0; i2 < 40; i2++) mx = fmaxf(mx, red[i2]);
    float se = 0.f;
    for (int i2 = 0; i2 < 40; i2++) se += expf(red[i2] - mx);
    float lse = mx + logf(se);
    for (int i2 = 0; i2 < 40; i2++) out[b*40 + i2] = red[i2] - lse;
  }
}

extern "C" void kernel_launch(void* const* d_in, const int* in_sizes, int n_in,
                              void* d_out, int out_size, void* d_ws, size_t ws_size,
                              hipStream_t stream) {
  (void)in_sizes; (void)n_in; (void)out_size; (void)ws_size;
  const float* x    = (const float*)d_in[0];
  const float* w1   = (const float*)d_in[1];
  const float* bn1g = (const float*)d_in[2];
  const float* bn1b = (const float*)d_in[3];
  const float* w2   = (const float*)d_in[4];
  const float* bn2g = (const float*)d_in[5];
  const float* bn2b = (const float*)d_in[6];
  const float* w3   = (const float*)d_in[7];
  const float* bn3g = (const float*)d_in[8];
  const float* bn3b = (const float*)d_in[9];
  const float* fc1w = (const float*)d_in[10];
  const float* fc1b = (const float*)d_in[11];
  const float* ln1g = (const float*)d_in[12];
  const float* ln1b = (const float*)d_in[13];
  const float* fc2w = (const float*)d_in[14];
  const float* fc2b = (const float*)d_in[15];
  const float* ln2g = (const float*)d_in[16];
  const float* ln2b = (const float*)d_in[17];
  const float* outw = (const float*)d_in[18];
  const float* outb = (const float*)d_in[19];
  float* out = (float*)d_out;

  float* ws = (float*)d_ws;
  size_t off = 0;
  float* xp1   = ws + off; off += 49152;
  int*   idx1  = (int*)(ws + off); off += 327680;
  float* hmax1 = ws + off; off += 1048576;
  float* hmin1 = ws + off; off += 1048576;
  float* feat3 = ws + off; off += 4194304;
  float* xp2   = ws + off; off += 1048576;
  float* hmax2 = ws + off; off += 3145728;   // also pdpart (knn partials)
  float* hmin2 = ws + off; off += 3145728;   // also idxpart
  int*   idx2  = (int*)(ws + off); off += 327680;
  float* wt2   = ws + off; off += 24576;
  float* wt3   = ws + off; off += 262144;
  float* x1T   = ws + off; off += 1048576;   // (b,c,n) transposed x1
  float* xx1   = ws + off; off += 16384;     // |x1|^2 per point
  float* scale1 = ws + off; off += 64;
  float* shift1 = ws + off; off += 64;
  float* scale2 = ws + off; off += 192;
  float* shift2 = ws + off; off += 192;
  float* scale3 = ws + off; off += 1024;
  float* shift3 = ws + off; off += 1024;
  double* stats1sh = (double*)(ws + off);      // 64*64*2 doubles
  double* stats2sh = stats1sh + 64*64*2;       // 64*192*2 doubles
  double* stats3   = stats2sh + 64*192*2;      // 1024*2 doubles
  unsigned* hmax3u = (unsigned*)(stats3 + 1024*2);  // 16384 u32
  unsigned* hmin3u = hmax3u + 16384;                // 16384 u32
  float* pdpart = hmax2;
  int*   idxpart = (int*)hmin2;

  size_t zero_bytes = (size_t)(64*64*2 + 64*192*2 + 1024*2)*8 + (size_t)16384*4;
  hipMemsetAsync(stats1sh, 0, zero_bytes, stream);
  hipMemsetAsync(hmin3u, 0xFF, (size_t)16384*4, stream);

  k_e2p1<<<64, 256, 0, stream>>>(x, xp1);
  k_knn1_part<<<256, 256, 0, stream>>>(x, pdpart, idxpart);
  k_knn2_merge<<<64, 256, 0, stream>>>(pdpart, idxpart, idx1);
  k_transpose<<<1024, 256, 0, stream>>>(w2, w3, wt2, wt3);
  k_conv1<<<1024, 256, 0, stream>>>(xp1, idx1, w1, hmax1, hmin1, stats1sh);
  k_bn_reduce<<<1, 64, 0, stream>>>(stats1sh, 64, 64, 327680.0, bn1g, bn1b, scale1, shift1);
  k_bn1_apply<<<4096, 256, 0, stream>>>(hmax1, hmin1, scale1, shift1, feat3, xp2, x1T, xx1);
  k_knn2g<<<512, 256, 0, stream>>>(x1T, xx1, pdpart, idxpart);
  k_knn2_merge<<<64, 256, 0, stream>>>(pdpart, idxpart, idx2);
  k_conv2<<<4096, 256, 0, stream>>>(xp2, idx2, wt2, hmax2, hmin2, stats2sh);
  k_bn_reduce<<<1, 192, 0, stream>>>(stats2sh, 64, 192, 327680.0, bn2g, bn2b, scale2, shift2);
  k_bn2_apply<<<12288, 256, 0, stream>>>(hmax2, hmin2, scale2, shift2, feat3);
  k_conv3<<<1024, 256, 0, stream>>>(feat3, wt3, stats3, hmax3u, hmin3u);
  k_bn_reduce<<<4, 256, 0, stream>>>(stats3, 1, 1024, 16384.0, bn3g, bn3b, scale3, shift3);
  k_head<<<16, 256, 0, stream>>>(hmax3u, hmin3u, scale3, shift3,
                                 fc1w, fc1b, ln1g, ln1b,
                                 fc2w, fc2b, ln2g, ln2b,
                                 outw, outb, out);
}

// Round 5
// 950.481 us; speedup vs baseline: 1.2173x; 1.2173x over previous
//
#include <hip/hip_runtime.h>
#include <math.h>

#define B_ 16
#define N_ 1024
#define KNN 20
#define NPAIR (B_*N_)

// ---------- helpers ----------
__device__ __forceinline__ unsigned fkey(float f) {
  unsigned u = __float_as_uint(f);
  return (u & 0x80000000u) ? ~u : (u | 0x80000000u);
}
__device__ __forceinline__ float fkeyinv(unsigned u) {
  unsigned b = (u & 0x80000000u) ? (u ^ 0x80000000u) : ~u;
  return __uint_as_float(b);
}

// Branchless (cndmask-chain) insertion into a descending sorted top-20.
__device__ __forceinline__ void topk_insert(float (&pdl)[KNN], int (&idl)[KNN], float d, int j) {
  pdl[KNN-1] = d; idl[KNN-1] = j;
  #pragma unroll
  for (int i = KNN-1; i > 0; i--) {
    float a = pdl[i-1], bv = pdl[i];
    int ai = idl[i-1], bi = idl[i];
    bool sw = bv > a;
    pdl[i-1] = sw ? bv : a;   pdl[i] = sw ? a  : bv;
    idl[i-1] = sw ? bi : ai;  idl[i] = sw ? ai : bi;
  }
}

// ---------- 1) e2p of raw points ----------
__global__ void k_e2p1(const float* __restrict__ x, float* __restrict__ xp1) {
  int p = blockIdx.x * 256 + threadIdx.x;
  if (p >= NPAIR) return;
  float a0 = x[p*3+0], a1 = x[p*3+1], a2 = x[p*3+2];
  float n = sqrtf(a0*a0 + a1*a1 + a2*a2);
  n = fmaxf(n, 1e-15f);
  float th = tanhf(0.1f * n);
  float sc = th / (0.1f * n);
  float ny = fmaxf(th * 10.0f, 1e-15f);
  float mxn = (1.0f - 4e-3f) / 0.1f;
  if (ny > mxn) sc *= mxn / ny;
  xp1[p*3+0] = sc*a0; xp1[p*3+1] = sc*a1; xp1[p*3+2] = sc*a2;
}

// ---------- 2) knn on raw 3-d points: 4-way candidate split ----------
__global__ void __launch_bounds__(256) k_knn1_part(const float* __restrict__ x,
        float* __restrict__ pdpart, int* __restrict__ idxpart) {
  __shared__ float P[N_*3];
  __shared__ float XX[N_];
  int blk = blockIdx.x;
  int b = blk >> 4, rc = (blk >> 2) & 3, cc = blk & 3;
  const float* xb = x + b*N_*3;
  for (int e = threadIdx.x; e < N_*3; e += 256) P[e] = xb[e];
  __syncthreads();
  for (int j = threadIdx.x; j < N_; j += 256) {
    float q0 = P[j*3], q1 = P[j*3+1], q2 = P[j*3+2];
    XX[j] = q0*q0 + q1*q1 + q2*q2;
  }
  __syncthreads();
  int r = rc*256 + threadIdx.x;
  float q0 = P[r*3], q1 = P[r*3+1], q2 = P[r*3+2];
  float xxq = XX[r];
  float pdl[KNN]; int idl[KNN];
  #pragma unroll
  for (int i = 0; i < KNN; i++) { pdl[i] = -__builtin_inff(); idl[i] = 0; }
  int cbase = cc*256;
  for (int jj = 0; jj < 256; jj++) {
    int j = cbase + jj;
    float dot = q0*P[j*3] + q1*P[j*3+1] + q2*P[j*3+2];
    float d = 2.0f*dot - xxq - XX[j];
    if (d > pdl[KNN-1]) topk_insert(pdl, idl, d, j);
  }
  int p = b*N_ + r;
  float* pe = pdpart + (size_t)p*80 + cc*20;
  int* ie = idxpart + (size_t)p*80 + cc*20;
  #pragma unroll
  for (int i = 0; i < KNN; i++) { pe[i] = pdl[i]; ie[i] = idl[i]; }
}

// ---------- 3) conv1 fused ----------
__global__ void __launch_bounds__(256) k_conv1(const float* __restrict__ xp1, const int* __restrict__ idx1,
                        const float* __restrict__ w1, float* __restrict__ hmax1,
                        float* __restrict__ hmin1, double* __restrict__ stats1sh) {
  __shared__ float F[4][KNN][6];
  __shared__ float red[4][64][2];
  int g = threadIdx.x >> 6, lane = threadIdx.x & 63;
  float w[6];
  #pragma unroll
  for (int c = 0; c < 6; c++) w[c] = w1[lane*6 + c];
  float sum = 0.f, sumsq = 0.f;
  int pbase = blockIdx.x * 16;
  for (int it = 0; it < 4; ++it) {
    int p = pbase + it*4 + g;
    if (lane < KNN) {
      int nb = idx1[p*KNN + lane];
      int bb = p >> 10;
      const float* xc = xp1 + p*3;
      const float* ft = xp1 + (bb*N_ + nb)*3;
      float x0 = ft[0], x1 = ft[1], x2v = ft[2];
      float c0 = xc[0], c1 = xc[1], c2 = xc[2];
      float X2 = x0*x0 + x1*x1 + x2v*x2v;
      float Y2 = c0*c0 + c1*c1 + c2*c2;
      float XY = -(x0*c0 + x1*c1 + x2v*c2);
      float den = fmaxf(1.0f + 0.02f*XY + 1e-4f*X2*Y2, 1e-15f);
      float s1 = (1.0f + 0.02f*XY + 0.01f*Y2) / den;
      float s2 = (1.0f - 0.01f*X2) / den;
      F[g][lane][0] = s1*x0 - s2*c0;
      F[g][lane][1] = s1*x1 - s2*c1;
      F[g][lane][2] = s1*x2v - s2*c2;
      F[g][lane][3] = c0; F[g][lane][4] = c1; F[g][lane][5] = c2;
    }
    __syncthreads();
    float mx = -__builtin_inff(), mn = __builtin_inff();
    for (int k = 0; k < KNN; k++) {
      float h = 0.f;
      #pragma unroll
      for (int c = 0; c < 6; c++) h = fmaf(w[c], F[g][k][c], h);
      mx = fmaxf(mx, h); mn = fminf(mn, h);
      sum += h; sumsq += h*h;
    }
    hmax1[p*64 + lane] = mx;
    hmin1[p*64 + lane] = mn;
    __syncthreads();
  }
  red[g][lane][0] = sum; red[g][lane][1] = sumsq;
  __syncthreads();
  if (g == 0) {
    float s  = red[0][lane][0] + red[1][lane][0] + red[2][lane][0] + red[3][lane][0];
    float s2 = red[0][lane][1] + red[1][lane][1] + red[2][lane][1] + red[3][lane][1];
    double* dst = stats1sh + ((size_t)(blockIdx.x & 63)*64 + lane)*2;
    atomicAdd(dst, (double)s);
    atomicAdd(dst + 1, (double)s2);
  }
}

// ---------- BN stat reduce ----------
__global__ void k_bn_reduce(const double* __restrict__ sh, int nsh, int nch, double cnt,
                            const float* __restrict__ g, const float* __restrict__ bb,
                            float* __restrict__ scale, float* __restrict__ shift) {
  int o = blockIdx.x * blockDim.x + threadIdx.x;
  if (o >= nch) return;
  double s = 0.0, s2 = 0.0;
  for (int i = 0; i < nsh; i++) {
    s  += sh[((size_t)i*nch + o)*2];
    s2 += sh[((size_t)i*nch + o)*2 + 1];
  }
  double m = s / cnt;
  double v = s2 / cnt - m*m;
  float a = g[o] / sqrtf((float)v + 1e-5f);
  scale[o] = a;
  shift[o] = bb[o] - a * (float)m;
}

// ---------- 5) BN1 apply + relu + e2p of x1 + transposed copy + |x1|^2 ----------
__global__ void __launch_bounds__(256) k_bn1_apply(const float* __restrict__ hmax1, const float* __restrict__ hmin1,
                            const float* __restrict__ scale1, const float* __restrict__ shift1,
                            float* __restrict__ feat3, float* __restrict__ xp2,
                            float* __restrict__ x1T, float* __restrict__ xx1) {
  int p = blockIdx.x*4 + (threadIdx.x >> 6);
  int c = threadIdx.x & 63;
  float a = scale1[c], t = shift1[c];
  float h = (a >= 0.f) ? hmax1[p*64 + c] : hmin1[p*64 + c];
  float x1 = fmaxf(fmaf(a, h, t), 0.f);
  feat3[p*256 + c] = x1;
  int b = p >> 10, n = p & 1023;
  x1T[((size_t)(b*64 + c))*1024 + n] = x1;
  float n2 = x1*x1;
  #pragma unroll
  for (int off = 32; off > 0; off >>= 1) n2 += __shfl_xor(n2, off);
  if (c == 0) xx1[p] = n2;
  float n1 = fmaxf(sqrtf(n2), 1e-15f);
  float th = tanhf(0.1f * n1);
  float sc = th / (0.1f * n1);
  float ny = fmaxf(th * 10.0f, 1e-15f);
  float mxn = (1.0f - 4e-3f) / 0.1f;
  if (ny > mxn) sc *= mxn / ny;
  xp2[p*64 + c] = sc * x1;
}

// ---------- 6) knn2: GEMM-tiled distances + LDS selection ----------
__global__ void __launch_bounds__(256) k_knn2g(const float* __restrict__ x1T,
        const float* __restrict__ xx1,
        float* __restrict__ pdpart, int* __restrict__ idxpart) {
  __shared__ __align__(16) float AsD[64*128];   // As (k-major) / D tile (reused)
  __shared__ __align__(16) float Bs[64*68];
  int tid = threadIdx.x;
  int blk = blockIdx.x;
  int b = blk >> 5, qc = (blk >> 2) & 7, cc = blk & 3;
  int qbase = qc*128, ccbase = cc*256;
  int tx = tid & 15, ty = tid >> 4;     // tx -> q-group, ty -> c-group
  int q0 = tx*8, c0 = ty*4;
  float pdl[KNN]; int idl[KNN];
  #pragma unroll
  for (int i = 0; i < KNN; i++) { pdl[i] = -__builtin_inff(); idl[i] = 0; }

  for (int st = 0; st < 4; ++st) {
    int cb0 = ccbase + st*64;
    #pragma unroll
    for (int r = 0; r < 8; r++) {
      int e = tid + r*256;
      int k = e >> 5, qf = e & 31;
      float4 v = *((const float4*)(x1T + ((size_t)(b*64 + k))*1024 + qbase + qf*4));
      *((float4*)(AsD + k*128 + qf*4)) = v;
    }
    #pragma unroll
    for (int r = 0; r < 4; r++) {
      int e = tid + r*256;
      int k = e >> 4, cf = e & 15;
      float4 v = *((const float4*)(x1T + ((size_t)(b*64 + k))*1024 + cb0 + cf*4));
      *((float4*)(Bs + k*68 + cf*4)) = v;
    }
    float4 xxc = *((const float4*)(xx1 + b*1024 + cb0 + c0));
    __syncthreads();
    float acc[8][4];
    #pragma unroll
    for (int i = 0; i < 8; i++)
      #pragma unroll
      for (int j = 0; j < 4; j++) acc[i][j] = 0.f;
    #pragma unroll 4
    for (int k = 0; k < 64; k++) {
      float4 a0 = *((const float4*)(AsD + k*128 + q0));
      float4 a1 = *((const float4*)(AsD + k*128 + q0 + 4));
      float4 bv = *((const float4*)(Bs + k*68 + c0));
      float av[8] = {a0.x,a0.y,a0.z,a0.w,a1.x,a1.y,a1.z,a1.w};
      float bw[4] = {bv.x,bv.y,bv.z,bv.w};
      #pragma unroll
      for (int i = 0; i < 8; i++)
        #pragma unroll
        for (int j = 0; j < 4; j++) acc[i][j] = fmaf(av[i], bw[j], acc[i][j]);
    }
    __syncthreads();
    float xxv[4] = {xxc.x, xxc.y, xxc.z, xxc.w};
    #pragma unroll
    for (int i = 0; i < 8; i++) {
      int q = q0 + i;
      #pragma unroll
      for (int j = 0; j < 4; j++) {
        int cl = c0 + j;
        AsD[q*64 + ((cl + q) & 63)] = 2.0f*acc[i][j] - xxv[j];
      }
    }
    __syncthreads();
    if (tid < 128) {
      int q = tid;
      for (int cl = 0; cl < 64; cl++) {
        float d = AsD[q*64 + ((cl + q) & 63)];
        if (d > pdl[KNN-1]) topk_insert(pdl, idl, d, cb0 + cl);
      }
    }
    __syncthreads();
  }
  if (tid < 128) {
    int p = b*N_ + qbase + tid;
    float* pe = pdpart + (size_t)p*80 + cc*20;
    int* ie = idxpart + (size_t)p*80 + cc*20;
    #pragma unroll
    for (int i = 0; i < KNN; i++) { pe[i] = pdl[i]; ie[i] = idl[i]; }
  }
}

// ---------- 7) merge 4 sorted top-20 chunks ----------
__global__ void k_knn2_merge(const float* __restrict__ pdpart, const int* __restrict__ idxpart,
                             int* __restrict__ idx2) {
  int p = blockIdx.x*256 + threadIdx.x;
  if (p >= NPAIR) return;
  const float* pe = pdpart + (size_t)p*80;
  const int* ie = idxpart + (size_t)p*80;
  int pos0 = 0, pos1 = 0, pos2 = 0, pos3 = 0;
  int* outp = idx2 + p*KNN;
  for (int t = 0; t < KNN; t++) {
    float best = -__builtin_inff(); int bi = 0x7FFFFFFF; int bc = 0;
    if (pos0 < KNN) { float pv = pe[pos0];      int iv = ie[pos0];      if (pv > best || (pv == best && iv < bi)) { best = pv; bi = iv; bc = 0; } }
    if (pos1 < KNN) { float pv = pe[20 + pos1]; int iv = ie[20 + pos1]; if (pv > best || (pv == best && iv < bi)) { best = pv; bi = iv; bc = 1; } }
    if (pos2 < KNN) { float pv = pe[40 + pos2]; int iv = ie[40 + pos2]; if (pv > best || (pv == best && iv < bi)) { best = pv; bi = iv; bc = 2; } }
    if (pos3 < KNN) { float pv = pe[60 + pos3]; int iv = ie[60 + pos3]; if (pv > best || (pv == best && iv < bi)) { best = pv; bi = iv; bc = 3; } }
    outp[t] = bi;
    if (bc == 0) pos0++; else if (bc == 1) pos1++; else if (bc == 2) pos2++; else pos3++;
  }
}

// ---------- 8) weight transposes ----------
__global__ void k_transpose(const float* __restrict__ w2, const float* __restrict__ w3,
                            float* __restrict__ wt2, float* __restrict__ wt3) {
  int i = blockIdx.x*256 + threadIdx.x;
  if (i < 192*128) { int o = i/128, c = i%128; wt2[c*192 + o] = w2[i]; }
  if (i < 1024*256) { int o = i/256, c = i%256; wt3[c*1024 + o] = w3[i]; }
}

// ---------- 9) conv2 fused: compact A-tile + split-K GEMM + stats + max/min ----------
// A holds only the mobius half (K=0..63); the xc half (K=64..127) reads from xcs
// (stride 68 -> the 4 group bases land on different banks; uniform-per-row reads broadcast).
__global__ void __launch_bounds__(256) k_conv2(const float* __restrict__ xp2,
    const int* __restrict__ idx2, const float* __restrict__ wt2,
    float* __restrict__ hmax2, float* __restrict__ hmin2, double* __restrict__ stats2sh) {
  __shared__ __align__(16) float A[80*68];      // 5440 floats; reused as stats/mmb scratch
  __shared__ __align__(16) float xcs[4*68];
  __shared__ float s1s[80], s2s[80];
  __shared__ int nbr[80];
  int tid = threadIdx.x;
  int ty = tid >> 4, tx = tid & 15;
  int p0 = blockIdx.x * 4;
  int b = p0 >> 10;
  if (tid < 256) {
    int g = tid >> 6, c = tid & 63;
    xcs[g*68 + c] = xp2[(size_t)(p0 + g)*64 + c];
  }
  if (tid < 80) nbr[tid] = idx2[p0*KNN + tid];
  __syncthreads();
  // phase1: A[r][0:64] = neighbor feat
  for (int e = tid; e < 80*16; e += 256) {
    int r = e >> 4, qq = e & 15;
    float4 v = *((const float4*)(xp2 + (size_t)(b*N_ + nbr[r])*64) + qq);
    *((float4*)(A + r*68) + qq) = v;
  }
  __syncthreads();
  // phase2: per-row mobius scalars (xc from xcs)
  if (tid < 80) {
    const float* Ar = A + tid*68;
    const float* xc = xcs + (tid/20)*68;
    float X2 = 0.f, XY = 0.f, Y2 = 0.f;
    for (int c2 = 0; c2 < 64; c2++) {
      float f = Ar[c2], xcv = xc[c2];
      X2 = fmaf(f, f, X2); XY = fmaf(-f, xcv, XY); Y2 = fmaf(xcv, xcv, Y2);
    }
    float den = fmaxf(1.0f + 0.02f*XY + 1e-4f*X2*Y2, 1e-15f);
    s1s[tid] = (1.0f + 0.02f*XY + 0.01f*Y2) / den;
    s2s[tid] = (1.0f - 0.01f*X2) / den;
  }
  __syncthreads();
  // phase3: A[r] = s1*A[r] - s2*xc
  for (int e = tid; e < 80*16; e += 256) {
    int r = e >> 4, qq = e & 15;
    float4 f = *((float4*)(A + r*68) + qq);
    float4 c4v = *((const float4*)(xcs + (r/20)*68) + qq);
    float s1 = s1s[r], s2 = s2s[r];
    f.x = s1*f.x - s2*c4v.x; f.y = s1*f.y - s2*c4v.y;
    f.z = s1*f.z - s2*c4v.z; f.w = s1*f.w - s2*c4v.w;
    *((float4*)(A + r*68) + qq) = f;
  }
  __syncthreads();
  // GEMM: 80x192, split K: 0..63 from A (mobius), 64..127 from xcs (xc half)
  float acc[5][12];
  #pragma unroll
  for (int i = 0; i < 5; i++)
    #pragma unroll
    for (int j = 0; j < 12; j++) acc[i][j] = 0.f;
  int grp[5];
  #pragma unroll
  for (int i = 0; i < 5; i++) grp[i] = (ty + 16*i) / 20;
  const float4* wtv = (const float4*)wt2;
  for (int kc = 0; kc < 64; kc++) {
    float4 w0 = wtv[kc*48 + tx];
    float4 w1 = wtv[kc*48 + 16 + tx];
    float4 w2 = wtv[kc*48 + 32 + tx];
    float wv[12] = {w0.x,w0.y,w0.z,w0.w, w1.x,w1.y,w1.z,w1.w, w2.x,w2.y,w2.z,w2.w};
    float ar[5];
    #pragma unroll
    for (int i = 0; i < 5; i++) ar[i] = A[(ty + 16*i)*68 + kc];
    #pragma unroll
    for (int i = 0; i < 5; i++) {
      #pragma unroll
      for (int j = 0; j < 12; j++) acc[i][j] = fmaf(ar[i], wv[j], acc[i][j]);
    }
  }
  for (int kc2 = 0; kc2 < 64; kc2++) {
    int kc = 64 + kc2;
    float4 w0 = wtv[kc*48 + tx];
    float4 w1 = wtv[kc*48 + 16 + tx];
    float4 w2 = wtv[kc*48 + 32 + tx];
    float wv[12] = {w0.x,w0.y,w0.z,w0.w, w1.x,w1.y,w1.z,w1.w, w2.x,w2.y,w2.z,w2.w};
    float ar[5];
    #pragma unroll
    for (int i = 0; i < 5; i++) ar[i] = xcs[grp[i]*68 + kc2];
    #pragma unroll
    for (int i = 0; i < 5; i++) {
      #pragma unroll
      for (int j = 0; j < 12; j++) acc[i][j] = fmaf(ar[i], wv[j], acc[i][j]);
    }
  }
  __syncthreads();   // A free for reuse now
  // stats: wave-level shuffle reduce, partials in A
  {
    float sv[12], qv[12];
    #pragma unroll
    for (int cc2 = 0; cc2 < 12; cc2++) {
      float s = 0.f, s2 = 0.f;
      #pragma unroll
      for (int i = 0; i < 5; i++) { float h = acc[i][cc2]; s += h; s2 += h*h; }
      sv[cc2] = s; qv[cc2] = s2;
    }
    #pragma unroll
    for (int cc2 = 0; cc2 < 12; cc2++) {
      sv[cc2] += __shfl_xor(sv[cc2], 16); qv[cc2] += __shfl_xor(qv[cc2], 16);
      sv[cc2] += __shfl_xor(sv[cc2], 32); qv[cc2] += __shfl_xor(qv[cc2], 32);
    }
    int lane = tid & 63, wv2 = tid >> 6;
    if (lane < 16) {
      #pragma unroll
      for (int cc2 = 0; cc2 < 12; cc2++) {
        A[wv2*400 + lane*25 + cc2*2]     = sv[cc2];
        A[wv2*400 + lane*25 + cc2*2 + 1] = qv[cc2];
      }
    }
  }
  __syncthreads();
  if (tid < 192) {
    int o = tid;
    int txo = (o & 63) >> 2, cc2 = (o >> 6)*4 + (o & 3);
    float s = 0.f, s2 = 0.f;
    #pragma unroll
    for (int w = 0; w < 4; w++) {
      s  += A[w*400 + txo*25 + cc2*2];
      s2 += A[w*400 + txo*25 + cc2*2 + 1];
    }
    double* dst = stats2sh + ((size_t)(blockIdx.x & 63)*192 + o)*2;
    atomicAdd(dst, (double)s); atomicAdd(dst + 1, (double)s2);
  }
  // max/min over k: 4 channels per round, 3 rounds (A reused as 80x68 transpose buf)
  for (int rnd = 0; rnd < 3; rnd++) {
    __syncthreads();
    #pragma unroll
    for (int i = 0; i < 5; i++) {
      #pragma unroll
      for (int cj = 0; cj < 4; cj++)
        A[(ty + 16*i)*68 + cj*16 + tx] = acc[i][rnd*4 + cj];
    }
    __syncthreads();
    if (tid < 64) {
      int g = tid >> 4, xx2 = tid & 15;
      float mx[4], mn[4];
      #pragma unroll
      for (int cj = 0; cj < 4; cj++) { mx[cj] = -__builtin_inff(); mn[cj] = __builtin_inff(); }
      for (int kk = 0; kk < KNN; kk++) {
        #pragma unroll
        for (int cj = 0; cj < 4; cj++) {
          float h = A[(g*20 + kk)*68 + cj*16 + xx2];
          mx[cj] = fmaxf(mx[cj], h); mn[cj] = fminf(mn[cj], h);
        }
      }
      #pragma unroll
      for (int cj = 0; cj < 4; cj++) {
        int o = rnd*64 + 4*xx2 + cj;
        hmax2[(size_t)(p0 + g)*192 + o] = mx[cj];
        hmin2[(size_t)(p0 + g)*192 + o] = mn[cj];
      }
    }
  }
}

// ---------- 10) BN2 apply ----------
__global__ void k_bn2_apply(const float* __restrict__ hmax2, const float* __restrict__ hmin2,
                            const float* __restrict__ scale2, const float* __restrict__ shift2,
                            float* __restrict__ feat3) {
  int e = blockIdx.x*256 + threadIdx.x;
  if (e >= NPAIR*192) return;
  int p = e / 192, o = e - p*192;
  float a = scale2[o], t = shift2[o];
  float h = (a >= 0.f) ? hmax2[e] : hmin2[e];
  feat3[(size_t)p*256 + 64 + o] = fmaxf(fmaf(a, h, t), 0.f);
}

// ---------- 11) conv3 GEMM + stats + max/min over n ----------
__global__ void __launch_bounds__(256) k_conv3(const float* __restrict__ feat3,
   const float* __restrict__ wt3, double* __restrict__ stats3,
   unsigned* __restrict__ hmax3u, unsigned* __restrict__ hmin3u) {
  __shared__ __align__(16) float A[64*68];
  __shared__ float buf[256*16];
  int tid = threadIdx.x, ty = tid >> 4, tx = tid & 15;
  int mt = blockIdx.x >> 2, cb = blockIdx.x & 3;
  int rowbase = mt*64;
  int b = rowbase >> 10;
  float acc[4][16];
  #pragma unroll
  for (int i = 0; i < 4; i++)
    #pragma unroll
    for (int j = 0; j < 16; j++) acc[i][j] = 0.f;
  for (int ch = 0; ch < 4; ch++) {
    int kb = ch*64;
    __syncthreads();
    for (int e = tid; e < 64*16; e += 256) {
      int rr = e >> 4, c4 = e & 15;
      *((float4*)(A + rr*68) + c4) = *((const float4*)(feat3 + (size_t)(rowbase + rr)*256 + kb) + c4);
    }
    __syncthreads();
    for (int kc = 0; kc < 64; kc++) {
      int kglob = kb + kc;
      float4 w[4];
      #pragma unroll
      for (int j = 0; j < 4; j++)
        w[j] = *((const float4*)(wt3 + (size_t)kglob*1024 + cb*256 + j*64 + 4*tx));
      float a[4];
      #pragma unroll
      for (int i = 0; i < 4; i++) a[i] = A[(ty + 16*i)*68 + kc];
      #pragma unroll
      for (int i = 0; i < 4; i++) {
        #pragma unroll
        for (int j = 0; j < 4; j++) {
          acc[i][j*4+0] = fmaf(a[i], w[j].x, acc[i][j*4+0]);
          acc[i][j*4+1] = fmaf(a[i], w[j].y, acc[i][j*4+1]);
          acc[i][j*4+2] = fmaf(a[i], w[j].z, acc[i][j*4+2]);
          acc[i][j*4+3] = fmaf(a[i], w[j].w, acc[i][j*4+3]);
        }
      }
    }
  }
  #pragma unroll
  for (int j = 0; j < 4; j++) {
    __syncthreads();
    #pragma unroll
    for (int q = 0; q < 4; q++) {
      float s = 0.f, s2 = 0.f, mx = -__builtin_inff(), mn = __builtin_inff();
      #pragma unroll
      for (int i = 0; i < 4; i++) {
        float h = acc[i][j*4+q];
        s += h; s2 += h*h; mx = fmaxf(mx, h); mn = fminf(mn, h);
      }
      float* bp = buf + tid*16 + q*4;
      bp[0] = s; bp[1] = s2; bp[2] = mx; bp[3] = mn;
    }
    __syncthreads();
    if (ty == 0) {
      #pragma unroll
      for (int q = 0; q < 4; q++) {
        float s = 0.f, s2 = 0.f, mx = -__builtin_inff(), mn = __builtin_inff();
        for (int yy = 0; yy < 16; yy++) {
          const float* bp = buf + (yy*16 + tx)*16 + q*4;
          s += bp[0]; s2 += bp[1]; mx = fmaxf(mx, bp[2]); mn = fminf(mn, bp[3]);
        }
        int o = cb*256 + j*64 + 4*tx + q;
        atomicAdd(stats3 + (size_t)o*2, (double)s);
        atomicAdd(stats3 + (size_t)o*2 + 1, (double)s2);
        atomicMax(hmax3u + b*1024 + o, fkey(mx));
        atomicMin(hmin3u + b*1024 + o, fkey(mn));
      }
    }
  }
}

// ---------- 12) head ----------
__device__ float blk_reduce(float v, float* red, int tid) {
  red[tid] = v; __syncthreads();
  for (int st = 128; st > 0; st >>= 1) {
    if (tid < st) red[tid] += red[tid + st];
    __syncthreads();
  }
  float r = red[0]; __syncthreads();
  return r;
}

__global__ void __launch_bounds__(256) k_head(const unsigned* __restrict__ hmax3u, const unsigned* __restrict__ hmin3u,
    const float* __restrict__ scale3, const float* __restrict__ shift3,
    const float* __restrict__ fc1w, const float* __restrict__ fc1b,
    const float* __restrict__ ln1g, const float* __restrict__ ln1b,
    const float* __restrict__ fc2w, const float* __restrict__ fc2b,
    const float* __restrict__ ln2g, const float* __restrict__ ln2b,
    const float* __restrict__ outw, const float* __restrict__ outb,
    float* __restrict__ out) {
  __shared__ __align__(16) float V[1024];
  __shared__ __align__(16) float H1[512];
  __shared__ __align__(16) float H2[256];
  __shared__ float red[256];
  int b = blockIdx.x, tid = threadIdx.x;
  for (int o = tid; o < 1024; o += 256) {
    float a = scale3[o];
    unsigned u = (a >= 0.f) ? hmax3u[b*1024 + o] : hmin3u[b*1024 + o];
    float h = fkeyinv(u);
    V[o] = fmaxf(fmaf(a, h, shift3[o]), 0.f);
  }
  __syncthreads();
  float h1v[2];
  #pragma unroll
  for (int ii = 0; ii < 2; ii++) {
    int o = tid + ii*256;
    const float4* wr = (const float4*)(fc1w + (size_t)o*1024);
    float s = 0.f;
    for (int c4 = 0; c4 < 256; c4++) {
      float4 w = wr[c4]; float4 vv = ((const float4*)V)[c4];
      s = fmaf(w.x, vv.x, s); s = fmaf(w.y, vv.y, s);
      s = fmaf(w.z, vv.z, s); s = fmaf(w.w, vv.w, s);
    }
    h1v[ii] = s + fc1b[o];
  }
  float s = h1v[0] + h1v[1];
  float s2 = h1v[0]*h1v[0] + h1v[1]*h1v[1];
  s = blk_reduce(s, red, tid);
  s2 = blk_reduce(s2, red, tid);
  float m = s / 512.f;
  float var = s2 / 512.f - m*m;
  float inv = 1.0f / sqrtf(var + 1e-5f);
  #pragma unroll
  for (int ii = 0; ii < 2; ii++) {
    int o = tid + ii*256;
    H1[o] = fmaxf((h1v[ii] - m)*inv*ln1g[o] + ln1b[o], 0.f);
  }
  __syncthreads();
  float h2v;
  {
    const float4* wr = (const float4*)(fc2w + (size_t)tid*512);
    float t = 0.f;
    for (int c4 = 0; c4 < 128; c4++) {
      float4 w = wr[c4]; float4 vv = ((const float4*)H1)[c4];
      t = fmaf(w.x, vv.x, t); t = fmaf(w.y, vv.y, t);
      t = fmaf(w.z, vv.z, t); t = fmaf(w.w, vv.w, t);
    }
    h2v = t + fc2b[tid];
  }
  float ss = blk_reduce(h2v, red, tid);
  float ss2 = blk_reduce(h2v*h2v, red, tid);
  float m2 = ss / 256.f;
  float var2 = ss2 / 256.f - m2*m2;
  float inv2 = 1.0f / sqrtf(var2 + 1e-5f);
  H2[tid] = fmaxf((h2v - m2)*inv2*ln2g[tid] + ln2b[tid], 0.f);
  __syncthreads();
  if (tid < 40) {
    const float4* wr = (const float4*)(outw + (size_t)tid*256);
    float t = 0.f;
    for (int c4 = 0; c4 < 64; c4++) {
      float4 w = wr[c4]; float4 vv = ((const float4*)H2)[c4];
      t = fmaf(w.x, vv.x, t); t = fmaf(w.y, vv.y, t);
      t = fmaf(w.z, vv.z, t); t = fmaf(w.w, vv.w, t);
    }
    red[tid] = t + outb[tid];
  }
  __syncthreads();
  if (tid == 0) {
    float mx = -__builtin_inff();
    for (int i2 = 0; i2 < 40; i2++) mx = fmaxf(mx, red[i2]);
    float se = 0.f;
    for (int i2 = 0; i2 < 40; i2++) se += expf(red[i2] - mx);
    float lse = mx + logf(se);
    for (int i2 = 0; i2 < 40; i2++) out[b*40 + i2] = red[i2] - lse;
  }
}

extern "C" void kernel_launch(void* const* d_in, const int* in_sizes, int n_in,
                              void* d_out, int out_size, void* d_ws, size_t ws_size,
                              hipStream_t stream) {
  (void)in_sizes; (void)n_in; (void)out_size; (void)ws_size;
  const float* x    = (const float*)d_in[0];
  const float* w1   = (const float*)d_in[1];
  const float* bn1g = (const float*)d_in[2];
  const float* bn1b = (const float*)d_in[3];
  const float* w2   = (const float*)d_in[4];
  const float* bn2g = (const float*)d_in[5];
  const float* bn2b = (const float*)d_in[6];
  const float* w3   = (const float*)d_in[7];
  const float* bn3g = (const float*)d_in[8];
  const float* bn3b = (const float*)d_in[9];
  const float* fc1w = (const float*)d_in[10];
  const float* fc1b = (const float*)d_in[11];
  const float* ln1g = (const float*)d_in[12];
  const float* ln1b = (const float*)d_in[13];
  const float* fc2w = (const float*)d_in[14];
  const float* fc2b = (const float*)d_in[15];
  const float* ln2g = (const float*)d_in[16];
  const float* ln2b = (const float*)d_in[17];
  const float* outw = (const float*)d_in[18];
  const float* outb = (const float*)d_in[19];
  float* out = (float*)d_out;

  float* ws = (float*)d_ws;
  size_t off = 0;
  float* xp1   = ws + off; off += 49152;
  int*   idx1  = (int*)(ws + off); off += 327680;
  float* hmax1 = ws + off; off += 1048576;
  float* hmin1 = ws + off; off += 1048576;
  float* feat3 = ws + off; off += 4194304;
  float* xp2   = ws + off; off += 1048576;
  float* hmax2 = ws + off; off += 3145728;   // also pdpart (knn partials)
  float* hmin2 = ws + off; off += 3145728;   // also idxpart
  int*   idx2  = (int*)(ws + off); off += 327680;
  float* wt2   = ws + off; off += 24576;
  float* wt3   = ws + off; off += 262144;
  float* x1T   = ws + off; off += 1048576;   // (b,c,n) transposed x1
  float* xx1   = ws + off; off += 16384;     // |x1|^2 per point
  float* scale1 = ws + off; off += 64;
  float* shift1 = ws + off; off += 64;
  float* scale2 = ws + off; off += 192;
  float* shift2 = ws + off; off += 192;
  float* scale3 = ws + off; off += 1024;
  float* shift3 = ws + off; off += 1024;
  double* stats1sh = (double*)(ws + off);      // 64*64*2 doubles
  double* stats2sh = stats1sh + 64*64*2;       // 64*192*2 doubles
  double* stats3   = stats2sh + 64*192*2;      // 1024*2 doubles
  unsigned* hmax3u = (unsigned*)(stats3 + 1024*2);  // 16384 u32
  unsigned* hmin3u = hmax3u + 16384;                // 16384 u32
  float* pdpart = hmax2;
  int*   idxpart = (int*)hmin2;

  size_t zero_bytes = (size_t)(64*64*2 + 64*192*2 + 1024*2)*8 + (size_t)16384*4;
  hipMemsetAsync(stats1sh, 0, zero_bytes, stream);
  hipMemsetAsync(hmin3u, 0xFF, (size_t)16384*4, stream);

  k_e2p1<<<64, 256, 0, stream>>>(x, xp1);
  k_knn1_part<<<256, 256, 0, stream>>>(x, pdpart, idxpart);
  k_knn2_merge<<<64, 256, 0, stream>>>(pdpart, idxpart, idx1);
  k_transpose<<<1024, 256, 0, stream>>>(w2, w3, wt2, wt3);
  k_conv1<<<1024, 256, 0, stream>>>(xp1, idx1, w1, hmax1, hmin1, stats1sh);
  k_bn_reduce<<<1, 64, 0, stream>>>(stats1sh, 64, 64, 327680.0, bn1g, bn1b, scale1, shift1);
  k_bn1_apply<<<4096, 256, 0, stream>>>(hmax1, hmin1, scale1, shift1, feat3, xp2, x1T, xx1);
  k_knn2g<<<512, 256, 0, stream>>>(x1T, xx1, pdpart, idxpart);
  k_knn2_merge<<<64, 256, 0, stream>>>(pdpart, idxpart, idx2);
  k_conv2<<<4096, 256, 0, stream>>>(xp2, idx2, wt2, hmax2, hmin2, stats2sh);
  k_bn_reduce<<<1, 192, 0, stream>>>(stats2sh, 64, 192, 327680.0, bn2g, bn2b, scale2, shift2);
  k_bn2_apply<<<12288, 256, 0, stream>>>(hmax2, hmin2, scale2, shift2, feat3);
  k_conv3<<<1024, 256, 0, stream>>>(feat3, wt3, stats3, hmax3u, hmin3u);
  k_bn_reduce<<<4, 256, 0, stream>>>(stats3, 1, 1024, 16384.0, bn3g, bn3b, scale3, shift3);
  k_head<<<16, 256, 0, stream>>>(hmax3u, hmin3u, scale3, shift3,
                                 fc1w, fc1b, ln1g, ln1b,
                                 fc2w, fc2b, ln2g, ln2b,
                                 outw, outb, out);
}

// Round 6
// 825.417 us; speedup vs baseline: 1.4017x; 1.1515x over previous
//
#include <hip/hip_runtime.h>
#include <math.h>

#define B_ 16
#define N_ 1024
#define KNN 20
#define NPAIR (B_*N_)

typedef __attribute__((ext_vector_type(8))) short bf16x8;
typedef __attribute__((ext_vector_type(4))) float f32x4;

// ---------- helpers ----------
__device__ __forceinline__ unsigned fkey(float f) {
  unsigned u = __float_as_uint(f);
  return (u & 0x80000000u) ? ~u : (u | 0x80000000u);
}
__device__ __forceinline__ float fkeyinv(unsigned u) {
  unsigned b = (u & 0x80000000u) ? (u ^ 0x80000000u) : ~u;
  return __uint_as_float(b);
}
__device__ __forceinline__ unsigned short f2bf(float x) {  // RNE float->bf16
  unsigned u = __float_as_uint(x);
  unsigned r = (u + 0x7FFFu + ((u >> 16) & 1u)) >> 16;
  return (unsigned short)r;
}

// Branchless (cndmask-chain) insertion into a descending sorted top-20.
__device__ __forceinline__ void topk_insert(float (&pdl)[KNN], int (&idl)[KNN], float d, int j) {
  pdl[KNN-1] = d; idl[KNN-1] = j;
  #pragma unroll
  for (int i = KNN-1; i > 0; i--) {
    float a = pdl[i-1], bv = pdl[i];
    int ai = idl[i-1], bi = idl[i];
    bool sw = bv > a;
    pdl[i-1] = sw ? bv : a;   pdl[i] = sw ? a  : bv;
    idl[i-1] = sw ? bi : ai;  idl[i] = sw ? ai : bi;
  }
}

// ---------- 1) e2p of raw points ----------
__global__ void k_e2p1(const float* __restrict__ x, float* __restrict__ xp1) {
  int p = blockIdx.x * 256 + threadIdx.x;
  if (p >= NPAIR) return;
  float a0 = x[p*3+0], a1 = x[p*3+1], a2 = x[p*3+2];
  float n = sqrtf(a0*a0 + a1*a1 + a2*a2);
  n = fmaxf(n, 1e-15f);
  float th = tanhf(0.1f * n);
  float sc = th / (0.1f * n);
  float ny = fmaxf(th * 10.0f, 1e-15f);
  float mxn = (1.0f - 4e-3f) / 0.1f;
  if (ny > mxn) sc *= mxn / ny;
  xp1[p*3+0] = sc*a0; xp1[p*3+1] = sc*a1; xp1[p*3+2] = sc*a2;
}

// ---------- 2) knn on raw 3-d points: 4-way candidate split ----------
__global__ void __launch_bounds__(256) k_knn1_part(const float* __restrict__ x,
        float* __restrict__ pdpart, int* __restrict__ idxpart) {
  __shared__ float P[N_*3];
  __shared__ float XX[N_];
  int blk = blockIdx.x;
  int b = blk >> 4, rc = (blk >> 2) & 3, cc = blk & 3;
  const float* xb = x + b*N_*3;
  for (int e = threadIdx.x; e < N_*3; e += 256) P[e] = xb[e];
  __syncthreads();
  for (int j = threadIdx.x; j < N_; j += 256) {
    float q0 = P[j*3], q1 = P[j*3+1], q2 = P[j*3+2];
    XX[j] = q0*q0 + q1*q1 + q2*q2;
  }
  __syncthreads();
  int r = rc*256 + threadIdx.x;
  float q0 = P[r*3], q1 = P[r*3+1], q2 = P[r*3+2];
  float xxq = XX[r];
  float pdl[KNN]; int idl[KNN];
  #pragma unroll
  for (int i = 0; i < KNN; i++) { pdl[i] = -__builtin_inff(); idl[i] = 0; }
  int cbase = cc*256;
  for (int jj = 0; jj < 256; jj++) {
    int j = cbase + jj;
    float dot = q0*P[j*3] + q1*P[j*3+1] + q2*P[j*3+2];
    float d = 2.0f*dot - xxq - XX[j];
    if (d > pdl[KNN-1]) topk_insert(pdl, idl, d, j);
  }
  int p = b*N_ + r;
  float* pe = pdpart + (size_t)p*80 + cc*20;
  int* ie = idxpart + (size_t)p*80 + cc*20;
  #pragma unroll
  for (int i = 0; i < KNN; i++) { pe[i] = pdl[i]; ie[i] = idl[i]; }
}

// ---------- 3) conv1 fused ----------
__global__ void __launch_bounds__(256) k_conv1(const float* __restrict__ xp1, const int* __restrict__ idx1,
                        const float* __restrict__ w1, float* __restrict__ hmax1,
                        float* __restrict__ hmin1, double* __restrict__ stats1sh) {
  __shared__ float F[4][KNN][6];
  __shared__ float red[4][64][2];
  int g = threadIdx.x >> 6, lane = threadIdx.x & 63;
  float w[6];
  #pragma unroll
  for (int c = 0; c < 6; c++) w[c] = w1[lane*6 + c];
  float sum = 0.f, sumsq = 0.f;
  int pbase = blockIdx.x * 16;
  for (int it = 0; it < 4; ++it) {
    int p = pbase + it*4 + g;
    if (lane < KNN) {
      int nb = idx1[p*KNN + lane];
      int bb = p >> 10;
      const float* xc = xp1 + p*3;
      const float* ft = xp1 + (bb*N_ + nb)*3;
      float x0 = ft[0], x1 = ft[1], x2v = ft[2];
      float c0 = xc[0], c1 = xc[1], c2 = xc[2];
      float X2 = x0*x0 + x1*x1 + x2v*x2v;
      float Y2 = c0*c0 + c1*c1 + c2*c2;
      float XY = -(x0*c0 + x1*c1 + x2v*c2);
      float den = fmaxf(1.0f + 0.02f*XY + 1e-4f*X2*Y2, 1e-15f);
      float s1 = (1.0f + 0.02f*XY + 0.01f*Y2) / den;
      float s2 = (1.0f - 0.01f*X2) / den;
      F[g][lane][0] = s1*x0 - s2*c0;
      F[g][lane][1] = s1*x1 - s2*c1;
      F[g][lane][2] = s1*x2v - s2*c2;
      F[g][lane][3] = c0; F[g][lane][4] = c1; F[g][lane][5] = c2;
    }
    __syncthreads();
    float mx = -__builtin_inff(), mn = __builtin_inff();
    for (int k = 0; k < KNN; k++) {
      float h = 0.f;
      #pragma unroll
      for (int c = 0; c < 6; c++) h = fmaf(w[c], F[g][k][c], h);
      mx = fmaxf(mx, h); mn = fminf(mn, h);
      sum += h; sumsq += h*h;
    }
    hmax1[p*64 + lane] = mx;
    hmin1[p*64 + lane] = mn;
    __syncthreads();
  }
  red[g][lane][0] = sum; red[g][lane][1] = sumsq;
  __syncthreads();
  if (g == 0) {
    float s  = red[0][lane][0] + red[1][lane][0] + red[2][lane][0] + red[3][lane][0];
    float s2 = red[0][lane][1] + red[1][lane][1] + red[2][lane][1] + red[3][lane][1];
    double* dst = stats1sh + ((size_t)(blockIdx.x & 63)*64 + lane)*2;
    atomicAdd(dst, (double)s);
    atomicAdd(dst + 1, (double)s2);
  }
}

// ---------- BN stat reduce ----------
__global__ void k_bn_reduce(const double* __restrict__ sh, int nsh, int nch, double cnt,
                            const float* __restrict__ g, const float* __restrict__ bb,
                            float* __restrict__ scale, float* __restrict__ shift) {
  int o = blockIdx.x * blockDim.x + threadIdx.x;
  if (o >= nch) return;
  double s = 0.0, s2 = 0.0;
  for (int i = 0; i < nsh; i++) {
    s  += sh[((size_t)i*nch + o)*2];
    s2 += sh[((size_t)i*nch + o)*2 + 1];
  }
  double m = s / cnt;
  double v = s2 / cnt - m*m;
  float a = g[o] / sqrtf((float)v + 1e-5f);
  scale[o] = a;
  shift[o] = bb[o] - a * (float)m;
}

// ---------- 5) BN1 apply + relu + e2p of x1 + transposed copy + |x1|^2 ----------
__global__ void __launch_bounds__(256) k_bn1_apply(const float* __restrict__ hmax1, const float* __restrict__ hmin1,
                            const float* __restrict__ scale1, const float* __restrict__ shift1,
                            unsigned short* __restrict__ feat3h, float* __restrict__ xp2,
                            float* __restrict__ x1T, float* __restrict__ xx1) {
  int p = blockIdx.x*4 + (threadIdx.x >> 6);
  int c = threadIdx.x & 63;
  float a = scale1[c], t = shift1[c];
  float h = (a >= 0.f) ? hmax1[p*64 + c] : hmin1[p*64 + c];
  float x1 = fmaxf(fmaf(a, h, t), 0.f);
  feat3h[(size_t)p*256 + c] = f2bf(x1);
  int b = p >> 10, n = p & 1023;
  x1T[((size_t)(b*64 + c))*1024 + n] = x1;
  float n2 = x1*x1;
  #pragma unroll
  for (int off = 32; off > 0; off >>= 1) n2 += __shfl_xor(n2, off);
  if (c == 0) xx1[p] = n2;
  float n1 = fmaxf(sqrtf(n2), 1e-15f);
  float th = tanhf(0.1f * n1);
  float sc = th / (0.1f * n1);
  float ny = fmaxf(th * 10.0f, 1e-15f);
  float mxn = (1.0f - 4e-3f) / 0.1f;
  if (ny > mxn) sc *= mxn / ny;
  xp2[p*64 + c] = sc * x1;
}

// ---------- 6) knn2: GEMM-tiled distances + LDS selection ----------
__global__ void __launch_bounds__(256) k_knn2g(const float* __restrict__ x1T,
        const float* __restrict__ xx1,
        float* __restrict__ pdpart, int* __restrict__ idxpart) {
  __shared__ __align__(16) float AsD[64*128];   // As (k-major) / D tile (reused)
  __shared__ __align__(16) float Bs[64*68];
  int tid = threadIdx.x;
  int blk = blockIdx.x;
  int b = blk >> 5, qc = (blk >> 2) & 7, cc = blk & 3;
  int qbase = qc*128, ccbase = cc*256;
  int tx = tid & 15, ty = tid >> 4;     // tx -> q-group, ty -> c-group
  int q0 = tx*8, c0 = ty*4;
  float pdl[KNN]; int idl[KNN];
  #pragma unroll
  for (int i = 0; i < KNN; i++) { pdl[i] = -__builtin_inff(); idl[i] = 0; }

  for (int st = 0; st < 4; ++st) {
    int cb0 = ccbase + st*64;
    #pragma unroll
    for (int r = 0; r < 8; r++) {
      int e = tid + r*256;
      int k = e >> 5, qf = e & 31;
      float4 v = *((const float4*)(x1T + ((size_t)(b*64 + k))*1024 + qbase + qf*4));
      *((float4*)(AsD + k*128 + qf*4)) = v;
    }
    #pragma unroll
    for (int r = 0; r < 4; r++) {
      int e = tid + r*256;
      int k = e >> 4, cf = e & 15;
      float4 v = *((const float4*)(x1T + ((size_t)(b*64 + k))*1024 + cb0 + cf*4));
      *((float4*)(Bs + k*68 + cf*4)) = v;
    }
    float4 xxc = *((const float4*)(xx1 + b*1024 + cb0 + c0));
    __syncthreads();
    float acc[8][4];
    #pragma unroll
    for (int i = 0; i < 8; i++)
      #pragma unroll
      for (int j = 0; j < 4; j++) acc[i][j] = 0.f;
    #pragma unroll 4
    for (int k = 0; k < 64; k++) {
      float4 a0 = *((const float4*)(AsD + k*128 + q0));
      float4 a1 = *((const float4*)(AsD + k*128 + q0 + 4));
      float4 bv = *((const float4*)(Bs + k*68 + c0));
      float av[8] = {a0.x,a0.y,a0.z,a0.w,a1.x,a1.y,a1.z,a1.w};
      float bw[4] = {bv.x,bv.y,bv.z,bv.w};
      #pragma unroll
      for (int i = 0; i < 8; i++)
        #pragma unroll
        for (int j = 0; j < 4; j++) acc[i][j] = fmaf(av[i], bw[j], acc[i][j]);
    }
    __syncthreads();
    float xxv[4] = {xxc.x, xxc.y, xxc.z, xxc.w};
    #pragma unroll
    for (int i = 0; i < 8; i++) {
      int q = q0 + i;
      #pragma unroll
      for (int j = 0; j < 4; j++) {
        int cl = c0 + j;
        AsD[q*64 + ((cl + q) & 63)] = 2.0f*acc[i][j] - xxv[j];
      }
    }
    __syncthreads();
    if (tid < 128) {
      int q = tid;
      for (int cl = 0; cl < 64; cl++) {
        float d = AsD[q*64 + ((cl + q) & 63)];
        if (d > pdl[KNN-1]) topk_insert(pdl, idl, d, cb0 + cl);
      }
    }
    __syncthreads();
  }
  if (tid < 128) {
    int p = b*N_ + qbase + tid;
    float* pe = pdpart + (size_t)p*80 + cc*20;
    int* ie = idxpart + (size_t)p*80 + cc*20;
    #pragma unroll
    for (int i = 0; i < KNN; i++) { pe[i] = pdl[i]; ie[i] = idl[i]; }
  }
}

// ---------- 7) merge 4 sorted top-20 chunks ----------
__global__ void k_knn2_merge(const float* __restrict__ pdpart, const int* __restrict__ idxpart,
                             int* __restrict__ idx2) {
  int p = blockIdx.x*256 + threadIdx.x;
  if (p >= NPAIR) return;
  const float* pe = pdpart + (size_t)p*80;
  const int* ie = idxpart + (size_t)p*80;
  int pos0 = 0, pos1 = 0, pos2 = 0, pos3 = 0;
  int* outp = idx2 + p*KNN;
  for (int t = 0; t < KNN; t++) {
    float best = -__builtin_inff(); int bi = 0x7FFFFFFF; int bc = 0;
    if (pos0 < KNN) { float pv = pe[pos0];      int iv = ie[pos0];      if (pv > best || (pv == best && iv < bi)) { best = pv; bi = iv; bc = 0; } }
    if (pos1 < KNN) { float pv = pe[20 + pos1]; int iv = ie[20 + pos1]; if (pv > best || (pv == best && iv < bi)) { best = pv; bi = iv; bc = 1; } }
    if (pos2 < KNN) { float pv = pe[40 + pos2]; int iv = ie[40 + pos2]; if (pv > best || (pv == best && iv < bi)) { best = pv; bi = iv; bc = 2; } }
    if (pos3 < KNN) { float pv = pe[60 + pos3]; int iv = ie[60 + pos3]; if (pv > best || (pv == best && iv < bi)) { best = pv; bi = iv; bc = 3; } }
    outp[t] = bi;
    if (bc == 0) pos0++; else if (bc == 1) pos1++; else if (bc == 2) pos2++; else pos3++;
  }
}

// ---------- 8) weight transposes / bf16 conversion ----------
__global__ void k_transpose(const float* __restrict__ w2, const float* __restrict__ w3,
                            float* __restrict__ wt2, unsigned short* __restrict__ wt3h) {
  int i = blockIdx.x*256 + threadIdx.x;
  if (i < 192*128) { int o = i/128, c = i%128; wt2[c*192 + o] = w2[i]; }
  if (i < 1024*256) { wt3h[i] = f2bf(w3[i]); }   // [o][c] o-major, k-contiguous
}

// ---------- 9) conv2 fused: compact A-tile + split-K GEMM (kc x4 unroll) + stats + max/min ----------
__global__ void __launch_bounds__(256) k_conv2(const float* __restrict__ xp2,
    const int* __restrict__ idx2, const float* __restrict__ wt2,
    float* __restrict__ hmax2, float* __restrict__ hmin2, double* __restrict__ stats2sh) {
  __shared__ __align__(16) float A[80*68];
  __shared__ __align__(16) float xcs[4*68];
  __shared__ float s1s[80], s2s[80];
  __shared__ int nbr[80];
  int tid = threadIdx.x;
  int ty = tid >> 4, tx = tid & 15;
  int p0 = blockIdx.x * 4;
  int b = p0 >> 10;
  {
    int g = tid >> 6, c = tid & 63;
    xcs[g*68 + c] = xp2[(size_t)(p0 + g)*64 + c];
  }
  if (tid < 80) nbr[tid] = idx2[p0*KNN + tid];
  __syncthreads();
  for (int e = tid; e < 80*16; e += 256) {
    int r = e >> 4, qq = e & 15;
    float4 v = *((const float4*)(xp2 + (size_t)(b*N_ + nbr[r])*64) + qq);
    *((float4*)(A + r*68) + qq) = v;
  }
  __syncthreads();
  if (tid < 80) {
    const float* Ar = A + tid*68;
    const float* xc = xcs + (tid/20)*68;
    float X2 = 0.f, XY = 0.f, Y2 = 0.f;
    for (int c2 = 0; c2 < 64; c2++) {
      float f = Ar[c2], xcv = xc[c2];
      X2 = fmaf(f, f, X2); XY = fmaf(-f, xcv, XY); Y2 = fmaf(xcv, xcv, Y2);
    }
    float den = fmaxf(1.0f + 0.02f*XY + 1e-4f*X2*Y2, 1e-15f);
    s1s[tid] = (1.0f + 0.02f*XY + 0.01f*Y2) / den;
    s2s[tid] = (1.0f - 0.01f*X2) / den;
  }
  __syncthreads();
  for (int e = tid; e < 80*16; e += 256) {
    int r = e >> 4, qq = e & 15;
    float4 f = *((float4*)(A + r*68) + qq);
    float4 c4v = *((const float4*)(xcs + (r/20)*68) + qq);
    float s1 = s1s[r], s2 = s2s[r];
    f.x = s1*f.x - s2*c4v.x; f.y = s1*f.y - s2*c4v.y;
    f.z = s1*f.z - s2*c4v.z; f.w = s1*f.w - s2*c4v.w;
    *((float4*)(A + r*68) + qq) = f;
  }
  __syncthreads();
  float acc[5][12];
  #pragma unroll
  for (int i = 0; i < 5; i++)
    #pragma unroll
    for (int j = 0; j < 12; j++) acc[i][j] = 0.f;
  int grp[5];
  #pragma unroll
  for (int i = 0; i < 5; i++) grp[i] = (ty + 16*i) / 20;
  const float4* wtv = (const float4*)wt2;
  // K 0..63 from A (mobius half), vectorized ds_read_b128 over 4 kc
  for (int kc = 0; kc < 64; kc += 4) {
    float4 ar4[5];
    #pragma unroll
    for (int i = 0; i < 5; i++) ar4[i] = *((const float4*)(A + (ty + 16*i)*68 + kc));
    #pragma unroll
    for (int u = 0; u < 4; u++) {
      int k = kc + u;
      float4 w0 = wtv[k*48 + tx];
      float4 w1 = wtv[k*48 + 16 + tx];
      float4 w2 = wtv[k*48 + 32 + tx];
      float wv[12] = {w0.x,w0.y,w0.z,w0.w, w1.x,w1.y,w1.z,w1.w, w2.x,w2.y,w2.z,w2.w};
      #pragma unroll
      for (int i = 0; i < 5; i++) {
        float ar = ((const float*)&ar4[i])[u];
        #pragma unroll
        for (int j = 0; j < 12; j++) acc[i][j] = fmaf(ar, wv[j], acc[i][j]);
      }
    }
  }
  // K 64..127 from xcs (xc half)
  for (int kc2 = 0; kc2 < 64; kc2 += 4) {
    float4 xc4[5];
    #pragma unroll
    for (int i = 0; i < 5; i++) xc4[i] = *((const float4*)(xcs + grp[i]*68 + kc2));
    #pragma unroll
    for (int u = 0; u < 4; u++) {
      int k = 64 + kc2 + u;
      float4 w0 = wtv[k*48 + tx];
      float4 w1 = wtv[k*48 + 16 + tx];
      float4 w2 = wtv[k*48 + 32 + tx];
      float wv[12] = {w0.x,w0.y,w0.z,w0.w, w1.x,w1.y,w1.z,w1.w, w2.x,w2.y,w2.z,w2.w};
      #pragma unroll
      for (int i = 0; i < 5; i++) {
        float ar = ((const float*)&xc4[i])[u];
        #pragma unroll
        for (int j = 0; j < 12; j++) acc[i][j] = fmaf(ar, wv[j], acc[i][j]);
      }
    }
  }
  __syncthreads();   // A free for reuse now
  {
    float sv[12], qv[12];
    #pragma unroll
    for (int cc2 = 0; cc2 < 12; cc2++) {
      float s = 0.f, s2 = 0.f;
      #pragma unroll
      for (int i = 0; i < 5; i++) { float h = acc[i][cc2]; s += h; s2 += h*h; }
      sv[cc2] = s; qv[cc2] = s2;
    }
    #pragma unroll
    for (int cc2 = 0; cc2 < 12; cc2++) {
      sv[cc2] += __shfl_xor(sv[cc2], 16); qv[cc2] += __shfl_xor(qv[cc2], 16);
      sv[cc2] += __shfl_xor(sv[cc2], 32); qv[cc2] += __shfl_xor(qv[cc2], 32);
    }
    int lane = tid & 63, wv2 = tid >> 6;
    if (lane < 16) {
      #pragma unroll
      for (int cc2 = 0; cc2 < 12; cc2++) {
        A[wv2*400 + lane*25 + cc2*2]     = sv[cc2];
        A[wv2*400 + lane*25 + cc2*2 + 1] = qv[cc2];
      }
    }
  }
  __syncthreads();
  if (tid < 192) {
    int o = tid;
    int txo = (o & 63) >> 2, cc2 = (o >> 6)*4 + (o & 3);
    float s = 0.f, s2 = 0.f;
    #pragma unroll
    for (int w = 0; w < 4; w++) {
      s  += A[w*400 + txo*25 + cc2*2];
      s2 += A[w*400 + txo*25 + cc2*2 + 1];
    }
    double* dst = stats2sh + ((size_t)(blockIdx.x & 63)*192 + o)*2;
    atomicAdd(dst, (double)s); atomicAdd(dst + 1, (double)s2);
  }
  for (int rnd = 0; rnd < 3; rnd++) {
    __syncthreads();
    #pragma unroll
    for (int i = 0; i < 5; i++) {
      #pragma unroll
      for (int cj = 0; cj < 4; cj++)
        A[(ty + 16*i)*68 + cj*16 + tx] = acc[i][rnd*4 + cj];
    }
    __syncthreads();
    if (tid < 64) {
      int g = tid >> 4, xx2 = tid & 15;
      float mx[4], mn[4];
      #pragma unroll
      for (int cj = 0; cj < 4; cj++) { mx[cj] = -__builtin_inff(); mn[cj] = __builtin_inff(); }
      for (int kk = 0; kk < KNN; kk++) {
        #pragma unroll
        for (int cj = 0; cj < 4; cj++) {
          float h = A[(g*20 + kk)*68 + cj*16 + xx2];
          mx[cj] = fmaxf(mx[cj], h); mn[cj] = fminf(mn[cj], h);
        }
      }
      #pragma unroll
      for (int cj = 0; cj < 4; cj++) {
        int o = rnd*64 + 4*xx2 + cj;
        hmax2[(size_t)(p0 + g)*192 + o] = mx[cj];
        hmin2[(size_t)(p0 + g)*192 + o] = mn[cj];
      }
    }
  }
}

// ---------- 10) BN2 apply (writes bf16 feat) ----------
__global__ void k_bn2_apply(const float* __restrict__ hmax2, const float* __restrict__ hmin2,
                            const float* __restrict__ scale2, const float* __restrict__ shift2,
                            unsigned short* __restrict__ feat3h) {
  int e = blockIdx.x*256 + threadIdx.x;
  if (e >= NPAIR*192) return;
  int p = e / 192, o = e - p*192;
  float a = scale2[o], t = shift2[o];
  float h = (a >= 0.f) ? hmax2[e] : hmin2[e];
  feat3h[(size_t)p*256 + 64 + o] = f2bf(fmaxf(fmaf(a, h, t), 0.f));
}

// ---------- 11) conv3 via bf16 MFMA + stats + max/min over n ----------
// Block: 64 rows x 256 cols (4 waves x 64 cols); K=256. A staged bf16 in LDS (stride 264).
__global__ void __launch_bounds__(256) k_conv3m(const unsigned short* __restrict__ feat3h,
   const unsigned short* __restrict__ wt3h, double* __restrict__ stats3sh,
   unsigned* __restrict__ hmax3u, unsigned* __restrict__ hmin3u) {
  __shared__ short As[64*264];   // 33792 B
  int tid = threadIdx.x;
  int mt = blockIdx.x >> 2, cb = blockIdx.x & 3;
  int rowbase = mt*64;
  int b = rowbase >> 10;
  // stage A: 64 rows x 256 bf16 (32 chunks of 8 per row)
  for (int e = tid; e < 64*32; e += 256) {
    int r = e >> 5, ch = e & 31;
    *((float4*)(As + r*264 + ch*8)) =
      *((const float4*)(feat3h + (size_t)(rowbase + r)*256 + ch*8));
  }
  __syncthreads();
  int wave = tid >> 6, lane = tid & 63;
  int quad = lane >> 4, lm = lane & 15;
  int colbase = cb*256 + wave*64;
  f32x4 acc[4][4];   // [ri][cj]
  #pragma unroll
  for (int ri = 0; ri < 4; ri++)
    #pragma unroll
    for (int cj = 0; cj < 4; cj++) acc[ri][cj] = (f32x4){0.f, 0.f, 0.f, 0.f};
  for (int kt = 0; kt < 8; kt++) {
    int k0 = kt*32 + quad*8;
    bf16x8 bf[4];
    #pragma unroll
    for (int cj = 0; cj < 4; cj++)
      bf[cj] = *((const bf16x8*)(wt3h + (size_t)(colbase + cj*16 + lm)*256 + k0));
    bf16x8 af[4];
    #pragma unroll
    for (int ri = 0; ri < 4; ri++)
      af[ri] = *((const bf16x8*)(As + (ri*16 + lm)*264 + k0));
    #pragma unroll
    for (int ri = 0; ri < 4; ri++)
      #pragma unroll
      for (int cj = 0; cj < 4; cj++)
        acc[ri][cj] = __builtin_amdgcn_mfma_f32_16x16x32_bf16(af[ri], bf[cj], acc[ri][cj], 0, 0, 0);
  }
  // epilogue: per-col sum/sumsq over 64 rows + max/min; cross-quad shuffles
  #pragma unroll
  for (int cj = 0; cj < 4; cj++) {
    float s = 0.f, s2 = 0.f, mx = -__builtin_inff(), mn = __builtin_inff();
    #pragma unroll
    for (int ri = 0; ri < 4; ri++) {
      #pragma unroll
      for (int reg = 0; reg < 4; reg++) {
        float h = acc[ri][cj][reg];
        s += h; s2 += h*h; mx = fmaxf(mx, h); mn = fminf(mn, h);
      }
    }
    s  += __shfl_xor(s, 16);  s  += __shfl_xor(s, 32);
    s2 += __shfl_xor(s2, 16); s2 += __shfl_xor(s2, 32);
    mx = fmaxf(mx, __shfl_xor(mx, 16)); mx = fmaxf(mx, __shfl_xor(mx, 32));
    mn = fminf(mn, __shfl_xor(mn, 16)); mn = fminf(mn, __shfl_xor(mn, 32));
    if (lane < 16) {
      int col = colbase + cj*16 + lane;
      double* dst = stats3sh + ((size_t)(blockIdx.x & 63)*1024 + col)*2;
      atomicAdd(dst, (double)s);
      atomicAdd(dst + 1, (double)s2);
      atomicMax(hmax3u + b*1024 + col, fkey(mx));
      atomicMin(hmin3u + b*1024 + col, fkey(mn));
    }
  }
}

// ---------- 12) head ----------
__device__ float blk_reduce(float v, float* red, int tid) {
  red[tid] = v; __syncthreads();
  for (int st = 128; st > 0; st >>= 1) {
    if (tid < st) red[tid] += red[tid + st];
    __syncthreads();
  }
  float r = red[0]; __syncthreads();
  return r;
}

__global__ void __launch_bounds__(256) k_head(const unsigned* __restrict__ hmax3u, const unsigned* __restrict__ hmin3u,
    const float* __restrict__ scale3, const float* __restrict__ shift3,
    const float* __restrict__ fc1w, const float* __restrict__ fc1b,
    const float* __restrict__ ln1g, const float* __restrict__ ln1b,
    const float* __restrict__ fc2w, const float* __restrict__ fc2b,
    const float* __restrict__ ln2g, const float* __restrict__ ln2b,
    const float* __restrict__ outw, const float* __restrict__ outb,
    float* __restrict__ out) {
  __shared__ __align__(16) float V[1024];
  __shared__ __align__(16) float H1[512];
  __shared__ __align__(16) float H2[256];
  __shared__ float red[256];
  int b = blockIdx.x, tid = threadIdx.x;
  for (int o = tid; o < 1024; o += 256) {
    float a = scale3[o];
    unsigned u = (a >= 0.f) ? hmax3u[b*1024 + o] : hmin3u[b*1024 + o];
    float h = fkeyinv(u);
    V[o] = fmaxf(fmaf(a, h, shift3[o]), 0.f);
  }
  __syncthreads();
  float h1v[2];
  #pragma unroll
  for (int ii = 0; ii < 2; ii++) {
    int o = tid + ii*256;
    const float4* wr = (const float4*)(fc1w + (size_t)o*1024);
    float s = 0.f;
    for (int c4 = 0; c4 < 256; c4++) {
      float4 w = wr[c4]; float4 vv = ((const float4*)V)[c4];
      s = fmaf(w.x, vv.x, s); s = fmaf(w.y, vv.y, s);
      s = fmaf(w.z, vv.z, s); s = fmaf(w.w, vv.w, s);
    }
    h1v[ii] = s + fc1b[o];
  }
  float s = h1v[0] + h1v[1];
  float s2 = h1v[0]*h1v[0] + h1v[1]*h1v[1];
  s = blk_reduce(s, red, tid);
  s2 = blk_reduce(s2, red, tid);
  float m = s / 512.f;
  float var = s2 / 512.f - m*m;
  float inv = 1.0f / sqrtf(var + 1e-5f);
  #pragma unroll
  for (int ii = 0; ii < 2; ii++) {
    int o = tid + ii*256;
    H1[o] = fmaxf((h1v[ii] - m)*inv*ln1g[o] + ln1b[o], 0.f);
  }
  __syncthreads();
  float h2v;
  {
    const float4* wr = (const float4*)(fc2w + (size_t)tid*512);
    float t = 0.f;
    for (int c4 = 0; c4 < 128; c4++) {
      float4 w = wr[c4]; float4 vv = ((const float4*)H1)[c4];
      t = fmaf(w.x, vv.x, t); t = fmaf(w.y, vv.y, t);
      t = fmaf(w.z, vv.z, t); t = fmaf(w.w, vv.w, t);
    }
    h2v = t + fc2b[tid];
  }
  float ss = blk_reduce(h2v, red, tid);
  float ss2 = blk_reduce(h2v*h2v, red, tid);
  float m2 = ss / 256.f;
  float var2 = ss2 / 256.f - m2*m2;
  float inv2 = 1.0f / sqrtf(var2 + 1e-5f);
  H2[tid] = fmaxf((h2v - m2)*inv2*ln2g[tid] + ln2b[tid], 0.f);
  __syncthreads();
  if (tid < 40) {
    const float4* wr = (const float4*)(outw + (size_t)tid*256);
    float t = 0.f;
    for (int c4 = 0; c4 < 64; c4++) {
      float4 w = wr[c4]; float4 vv = ((const float4*)H2)[c4];
      t = fmaf(w.x, vv.x, t); t = fmaf(w.y, vv.y, t);
      t = fmaf(w.z, vv.z, t); t = fmaf(w.w, vv.w, t);
    }
    red[tid] = t + outb[tid];
  }
  __syncthreads();
  if (tid == 0) {
    float mx = -__builtin_inff();
    for (int i2 = 0; i2 < 40; i2++) mx = fmaxf(mx, red[i2]);
    float se = 0.f;
    for (int i2 = 0; i2 < 40; i2++) se += expf(red[i2] - mx);
    float lse = mx + logf(se);
    for (int i2 = 0; i2 < 40; i2++) out[b*40 + i2] = red[i2] - lse;
  }
}

extern "C" void kernel_launch(void* const* d_in, const int* in_sizes, int n_in,
                              void* d_out, int out_size, void* d_ws, size_t ws_size,
                              hipStream_t stream) {
  (void)in_sizes; (void)n_in; (void)out_size; (void)ws_size;
  const float* x    = (const float*)d_in[0];
  const float* w1   = (const float*)d_in[1];
  const float* bn1g = (const float*)d_in[2];
  const float* bn1b = (const float*)d_in[3];
  const float* w2   = (const float*)d_in[4];
  const float* bn2g = (const float*)d_in[5];
  const float* bn2b = (const float*)d_in[6];
  const float* w3   = (const float*)d_in[7];
  const float* bn3g = (const float*)d_in[8];
  const float* bn3b = (const float*)d_in[9];
  const float* fc1w = (const float*)d_in[10];
  const float* fc1b = (const float*)d_in[11];
  const float* ln1g = (const float*)d_in[12];
  const float* ln1b = (const float*)d_in[13];
  const float* fc2w = (const float*)d_in[14];
  const float* fc2b = (const float*)d_in[15];
  const float* ln2g = (const float*)d_in[16];
  const float* ln2b = (const float*)d_in[17];
  const float* outw = (const float*)d_in[18];
  const float* outb = (const float*)d_in[19];
  float* out = (float*)d_out;

  float* ws = (float*)d_ws;
  size_t off = 0;
  float* xp1   = ws + off; off += 49152;
  int*   idx1  = (int*)(ws + off); off += 327680;
  float* hmax1 = ws + off; off += 1048576;
  float* hmin1 = ws + off; off += 1048576;
  unsigned short* feat3h = (unsigned short*)(ws + off); off += 2097152;  // 16384x256 bf16
  float* xp2   = ws + off; off += 1048576;
  float* hmax2 = ws + off; off += 3145728;   // also pdpart (knn partials)
  float* hmin2 = ws + off; off += 3145728;   // also idxpart
  int*   idx2  = (int*)(ws + off); off += 327680;
  float* wt2   = ws + off; off += 24576;
  unsigned short* wt3h = (unsigned short*)(ws + off); off += 131072;     // 1024x256 bf16
  float* x1T   = ws + off; off += 1048576;   // (b,c,n) transposed x1
  float* xx1   = ws + off; off += 16384;     // |x1|^2 per point
  float* scale1 = ws + off; off += 64;
  float* shift1 = ws + off; off += 64;
  float* scale2 = ws + off; off += 192;
  float* shift2 = ws + off; off += 192;
  float* scale3 = ws + off; off += 1024;
  float* shift3 = ws + off; off += 1024;
  double* stats1sh = (double*)(ws + off);           // 64*64*2 doubles
  double* stats2sh = stats1sh + 64*64*2;            // 64*192*2 doubles
  double* stats3sh = stats2sh + 64*192*2;           // 64*1024*2 doubles
  unsigned* hmax3u = (unsigned*)(stats3sh + (size_t)64*1024*2);  // 16384 u32
  unsigned* hmin3u = hmax3u + 16384;                             // 16384 u32
  float* pdpart = hmax2;
  int*   idxpart = (int*)hmin2;

  size_t zero_bytes = ((size_t)64*64*2 + (size_t)64*192*2 + (size_t)64*1024*2)*8 + (size_t)16384*4;
  hipMemsetAsync(stats1sh, 0, zero_bytes, stream);
  hipMemsetAsync(hmin3u, 0xFF, (size_t)16384*4, stream);

  k_e2p1<<<64, 256, 0, stream>>>(x, xp1);
  k_knn1_part<<<256, 256, 0, stream>>>(x, pdpart, idxpart);
  k_knn2_merge<<<64, 256, 0, stream>>>(pdpart, idxpart, idx1);
  k_transpose<<<1024, 256, 0, stream>>>(w2, w3, wt2, wt3h);
  k_conv1<<<1024, 256, 0, stream>>>(xp1, idx1, w1, hmax1, hmin1, stats1sh);
  k_bn_reduce<<<1, 64, 0, stream>>>(stats1sh, 64, 64, 327680.0, bn1g, bn1b, scale1, shift1);
  k_bn1_apply<<<4096, 256, 0, stream>>>(hmax1, hmin1, scale1, shift1, feat3h, xp2, x1T, xx1);
  k_knn2g<<<512, 256, 0, stream>>>(x1T, xx1, pdpart, idxpart);
  k_knn2_merge<<<64, 256, 0, stream>>>(pdpart, idxpart, idx2);
  k_conv2<<<4096, 256, 0, stream>>>(xp2, idx2, wt2, hmax2, hmin2, stats2sh);
  k_bn_reduce<<<1, 192, 0, stream>>>(stats2sh, 64, 192, 327680.0, bn2g, bn2b, scale2, shift2);
  k_bn2_apply<<<12288, 256, 0, stream>>>(hmax2, hmin2, scale2, shift2, feat3h);
  k_conv3m<<<1024, 256, 0, stream>>>(feat3h, wt3h, stats3sh, hmax3u, hmin3u);
  k_bn_reduce<<<4, 256, 0, stream>>>(stats3sh, 64, 1024, 16384.0, bn3g, bn3b, scale3, shift3);
  k_head<<<16, 256, 0, stream>>>(hmax3u, hmin3u, scale3, shift3,
                                 fc1w, fc1b, ln1g, ln1b,
                                 fc2w, fc2b, ln2g, ln2b,
                                 outw, outb, out);
}

// Round 7
// 687.940 us; speedup vs baseline: 1.6819x; 1.1998x over previous
//
#include <hip/hip_runtime.h>
#include <math.h>

#define B_ 16
#define N_ 1024
#define KNN 20
#define NPAIR (B_*N_)

typedef __attribute__((ext_vector_type(8))) short bf16x8;
typedef __attribute__((ext_vector_type(4))) float f32x4;

// ---------- helpers ----------
__device__ __forceinline__ unsigned fkey(float f) {
  unsigned u = __float_as_uint(f);
  return (u & 0x80000000u) ? ~u : (u | 0x80000000u);
}
__device__ __forceinline__ float fkeyinv(unsigned u) {
  unsigned b = (u & 0x80000000u) ? (u ^ 0x80000000u) : ~u;
  return __uint_as_float(b);
}
__device__ __forceinline__ unsigned short f2bf(float x) {  // RNE float->bf16
  unsigned u = __float_as_uint(x);
  unsigned r = (u + 0x7FFFu + ((u >> 16) & 1u)) >> 16;
  return (unsigned short)r;
}

// Branchless (cndmask-chain) insertion into a descending sorted top-20.
__device__ __forceinline__ void topk_insert(float (&pdl)[KNN], int (&idl)[KNN], float d, int j) {
  pdl[KNN-1] = d; idl[KNN-1] = j;
  #pragma unroll
  for (int i = KNN-1; i > 0; i--) {
    float a = pdl[i-1], bv = pdl[i];
    int ai = idl[i-1], bi = idl[i];
    bool sw = bv > a;
    pdl[i-1] = sw ? bv : a;   pdl[i] = sw ? a  : bv;
    idl[i-1] = sw ? bi : ai;  idl[i] = sw ? ai : bi;
  }
}

// ---------- 1) e2p of raw points ----------
__global__ void k_e2p1(const float* __restrict__ x, float* __restrict__ xp1) {
  int p = blockIdx.x * 256 + threadIdx.x;
  if (p >= NPAIR) return;
  float a0 = x[p*3+0], a1 = x[p*3+1], a2 = x[p*3+2];
  float n = sqrtf(a0*a0 + a1*a1 + a2*a2);
  n = fmaxf(n, 1e-15f);
  float th = tanhf(0.1f * n);
  float sc = th / (0.1f * n);
  float ny = fmaxf(th * 10.0f, 1e-15f);
  float mxn = (1.0f - 4e-3f) / 0.1f;
  if (ny > mxn) sc *= mxn / ny;
  xp1[p*3+0] = sc*a0; xp1[p*3+1] = sc*a1; xp1[p*3+2] = sc*a2;
}

// ---------- 2) knn on raw 3-d points: 4-way candidate split ----------
__global__ void __launch_bounds__(256) k_knn1_part(const float* __restrict__ x,
        float* __restrict__ pdpart, int* __restrict__ idxpart) {
  __shared__ float P[N_*3];
  __shared__ float XX[N_];
  int blk = blockIdx.x;
  int b = blk >> 4, rc = (blk >> 2) & 3, cc = blk & 3;
  const float* xb = x + b*N_*3;
  for (int e = threadIdx.x; e < N_*3; e += 256) P[e] = xb[e];
  __syncthreads();
  for (int j = threadIdx.x; j < N_; j += 256) {
    float q0 = P[j*3], q1 = P[j*3+1], q2 = P[j*3+2];
    XX[j] = q0*q0 + q1*q1 + q2*q2;
  }
  __syncthreads();
  int r = rc*256 + threadIdx.x;
  float q0 = P[r*3], q1 = P[r*3+1], q2 = P[r*3+2];
  float xxq = XX[r];
  float pdl[KNN]; int idl[KNN];
  #pragma unroll
  for (int i = 0; i < KNN; i++) { pdl[i] = -__builtin_inff(); idl[i] = 0; }
  int cbase = cc*256;
  for (int jj = 0; jj < 256; jj++) {
    int j = cbase + jj;
    float dot = q0*P[j*3] + q1*P[j*3+1] + q2*P[j*3+2];
    float d = 2.0f*dot - xxq - XX[j];
    if (d > pdl[KNN-1]) topk_insert(pdl, idl, d, j);
  }
  int p = b*N_ + r;
  float* pe = pdpart + (size_t)p*80 + cc*20;
  int* ie = idxpart + (size_t)p*80 + cc*20;
  #pragma unroll
  for (int i = 0; i < KNN; i++) { pe[i] = pdl[i]; ie[i] = idl[i]; }
}

// ---------- 3) conv1 fused ----------
__global__ void __launch_bounds__(256) k_conv1(const float* __restrict__ xp1, const int* __restrict__ idx1,
                        const float* __restrict__ w1, float* __restrict__ hmax1,
                        float* __restrict__ hmin1, double* __restrict__ stats1sh) {
  __shared__ float F[4][KNN][6];
  __shared__ float red[4][64][2];
  int g = threadIdx.x >> 6, lane = threadIdx.x & 63;
  float w[6];
  #pragma unroll
  for (int c = 0; c < 6; c++) w[c] = w1[lane*6 + c];
  float sum = 0.f, sumsq = 0.f;
  int pbase = blockIdx.x * 16;
  for (int it = 0; it < 4; ++it) {
    int p = pbase + it*4 + g;
    if (lane < KNN) {
      int nb = idx1[p*KNN + lane];
      int bb = p >> 10;
      const float* xc = xp1 + p*3;
      const float* ft = xp1 + (bb*N_ + nb)*3;
      float x0 = ft[0], x1 = ft[1], x2v = ft[2];
      float c0 = xc[0], c1 = xc[1], c2 = xc[2];
      float X2 = x0*x0 + x1*x1 + x2v*x2v;
      float Y2 = c0*c0 + c1*c1 + c2*c2;
      float XY = -(x0*c0 + x1*c1 + x2v*c2);
      float den = fmaxf(1.0f + 0.02f*XY + 1e-4f*X2*Y2, 1e-15f);
      float s1 = (1.0f + 0.02f*XY + 0.01f*Y2) / den;
      float s2 = (1.0f - 0.01f*X2) / den;
      F[g][lane][0] = s1*x0 - s2*c0;
      F[g][lane][1] = s1*x1 - s2*c1;
      F[g][lane][2] = s1*x2v - s2*c2;
      F[g][lane][3] = c0; F[g][lane][4] = c1; F[g][lane][5] = c2;
    }
    __syncthreads();
    float mx = -__builtin_inff(), mn = __builtin_inff();
    for (int k = 0; k < KNN; k++) {
      float h = 0.f;
      #pragma unroll
      for (int c = 0; c < 6; c++) h = fmaf(w[c], F[g][k][c], h);
      mx = fmaxf(mx, h); mn = fminf(mn, h);
      sum += h; sumsq += h*h;
    }
    hmax1[p*64 + lane] = mx;
    hmin1[p*64 + lane] = mn;
    __syncthreads();
  }
  red[g][lane][0] = sum; red[g][lane][1] = sumsq;
  __syncthreads();
  if (g == 0) {
    float s  = red[0][lane][0] + red[1][lane][0] + red[2][lane][0] + red[3][lane][0];
    float s2 = red[0][lane][1] + red[1][lane][1] + red[2][lane][1] + red[3][lane][1];
    double* dst = stats1sh + ((size_t)(blockIdx.x & 63)*64 + lane)*2;
    atomicAdd(dst, (double)s);
    atomicAdd(dst + 1, (double)s2);
  }
}

// ---------- BN stat reduce ----------
__global__ void k_bn_reduce(const double* __restrict__ sh, int nsh, int nch, double cnt,
                            const float* __restrict__ g, const float* __restrict__ bb,
                            float* __restrict__ scale, float* __restrict__ shift) {
  int o = blockIdx.x * blockDim.x + threadIdx.x;
  if (o >= nch) return;
  double s = 0.0, s2 = 0.0;
  for (int i = 0; i < nsh; i++) {
    s  += sh[((size_t)i*nch + o)*2];
    s2 += sh[((size_t)i*nch + o)*2 + 1];
  }
  double m = s / cnt;
  double v = s2 / cnt - m*m;
  float a = g[o] / sqrtf((float)v + 1e-5f);
  scale[o] = a;
  shift[o] = bb[o] - a * (float)m;
}

// ---------- 5) BN1 apply + relu + e2p of x1 + transposed copy + |x1|^2 ----------
__global__ void __launch_bounds__(256) k_bn1_apply(const float* __restrict__ hmax1, const float* __restrict__ hmin1,
                            const float* __restrict__ scale1, const float* __restrict__ shift1,
                            unsigned short* __restrict__ feat3h, float* __restrict__ xp2,
                            float* __restrict__ x1T, float* __restrict__ xx1) {
  int p = blockIdx.x*4 + (threadIdx.x >> 6);
  int c = threadIdx.x & 63;
  float a = scale1[c], t = shift1[c];
  float h = (a >= 0.f) ? hmax1[p*64 + c] : hmin1[p*64 + c];
  float x1 = fmaxf(fmaf(a, h, t), 0.f);
  feat3h[(size_t)p*256 + c] = f2bf(x1);
  int b = p >> 10, n = p & 1023;
  x1T[((size_t)(b*64 + c))*1024 + n] = x1;
  float n2 = x1*x1;
  #pragma unroll
  for (int off = 32; off > 0; off >>= 1) n2 += __shfl_xor(n2, off);
  if (c == 0) xx1[p] = n2;
  float n1 = fmaxf(sqrtf(n2), 1e-15f);
  float th = tanhf(0.1f * n1);
  float sc = th / (0.1f * n1);
  float ny = fmaxf(th * 10.0f, 1e-15f);
  float mxn = (1.0f - 4e-3f) / 0.1f;
  if (ny > mxn) sc *= mxn / ny;
  xp2[p*64 + c] = sc * x1;
}

// ---------- 6) knn2: GEMM-tiled distances + LDS selection ----------
__global__ void __launch_bounds__(256) k_knn2g(const float* __restrict__ x1T,
        const float* __restrict__ xx1,
        float* __restrict__ pdpart, int* __restrict__ idxpart) {
  __shared__ __align__(16) float AsD[64*128];   // As (k-major) / D tile (reused)
  __shared__ __align__(16) float Bs[64*68];
  int tid = threadIdx.x;
  int blk = blockIdx.x;
  int b = blk >> 5, qc = (blk >> 2) & 7, cc = blk & 3;
  int qbase = qc*128, ccbase = cc*256;
  int tx = tid & 15, ty = tid >> 4;     // tx -> q-group, ty -> c-group
  int q0 = tx*8, c0 = ty*4;
  float pdl[KNN]; int idl[KNN];
  #pragma unroll
  for (int i = 0; i < KNN; i++) { pdl[i] = -__builtin_inff(); idl[i] = 0; }

  for (int st = 0; st < 4; ++st) {
    int cb0 = ccbase + st*64;
    #pragma unroll
    for (int r = 0; r < 8; r++) {
      int e = tid + r*256;
      int k = e >> 5, qf = e & 31;
      float4 v = *((const float4*)(x1T + ((size_t)(b*64 + k))*1024 + qbase + qf*4));
      *((float4*)(AsD + k*128 + qf*4)) = v;
    }
    #pragma unroll
    for (int r = 0; r < 4; r++) {
      int e = tid + r*256;
      int k = e >> 4, cf = e & 15;
      float4 v = *((const float4*)(x1T + ((size_t)(b*64 + k))*1024 + cb0 + cf*4));
      *((float4*)(Bs + k*68 + cf*4)) = v;
    }
    float4 xxc = *((const float4*)(xx1 + b*1024 + cb0 + c0));
    __syncthreads();
    float acc[8][4];
    #pragma unroll
    for (int i = 0; i < 8; i++)
      #pragma unroll
      for (int j = 0; j < 4; j++) acc[i][j] = 0.f;
    #pragma unroll 4
    for (int k = 0; k < 64; k++) {
      float4 a0 = *((const float4*)(AsD + k*128 + q0));
      float4 a1 = *((const float4*)(AsD + k*128 + q0 + 4));
      float4 bv = *((const float4*)(Bs + k*68 + c0));
      float av[8] = {a0.x,a0.y,a0.z,a0.w,a1.x,a1.y,a1.z,a1.w};
      float bw[4] = {bv.x,bv.y,bv.z,bv.w};
      #pragma unroll
      for (int i = 0; i < 8; i++)
        #pragma unroll
        for (int j = 0; j < 4; j++) acc[i][j] = fmaf(av[i], bw[j], acc[i][j]);
    }
    __syncthreads();
    float xxv[4] = {xxc.x, xxc.y, xxc.z, xxc.w};
    #pragma unroll
    for (int i = 0; i < 8; i++) {
      int q = q0 + i;
      #pragma unroll
      for (int j = 0; j < 4; j++) {
        int cl = c0 + j;
        AsD[q*64 + ((cl + q) & 63)] = 2.0f*acc[i][j] - xxv[j];
      }
    }
    __syncthreads();
    if (tid < 128) {
      int q = tid;
      for (int cl = 0; cl < 64; cl++) {
        float d = AsD[q*64 + ((cl + q) & 63)];
        if (d > pdl[KNN-1]) topk_insert(pdl, idl, d, cb0 + cl);
      }
    }
    __syncthreads();
  }
  if (tid < 128) {
    int p = b*N_ + qbase + tid;
    float* pe = pdpart + (size_t)p*80 + cc*20;
    int* ie = idxpart + (size_t)p*80 + cc*20;
    #pragma unroll
    for (int i = 0; i < KNN; i++) { pe[i] = pdl[i]; ie[i] = idl[i]; }
  }
}

// ---------- 7) merge 4 sorted top-20 chunks ----------
__global__ void k_knn2_merge(const float* __restrict__ pdpart, const int* __restrict__ idxpart,
                             int* __restrict__ idx2) {
  int p = blockIdx.x*256 + threadIdx.x;
  if (p >= NPAIR) return;
  const float* pe = pdpart + (size_t)p*80;
  const int* ie = idxpart + (size_t)p*80;
  int pos0 = 0, pos1 = 0, pos2 = 0, pos3 = 0;
  int* outp = idx2 + p*KNN;
  for (int t = 0; t < KNN; t++) {
    float best = -__builtin_inff(); int bi = 0x7FFFFFFF; int bc = 0;
    if (pos0 < KNN) { float pv = pe[pos0];      int iv = ie[pos0];      if (pv > best || (pv == best && iv < bi)) { best = pv; bi = iv; bc = 0; } }
    if (pos1 < KNN) { float pv = pe[20 + pos1]; int iv = ie[20 + pos1]; if (pv > best || (pv == best && iv < bi)) { best = pv; bi = iv; bc = 1; } }
    if (pos2 < KNN) { float pv = pe[40 + pos2]; int iv = ie[40 + pos2]; if (pv > best || (pv == best && iv < bi)) { best = pv; bi = iv; bc = 2; } }
    if (pos3 < KNN) { float pv = pe[60 + pos3]; int iv = ie[60 + pos3]; if (pv > best || (pv == best && iv < bi)) { best = pv; bi = iv; bc = 3; } }
    outp[t] = bi;
    if (bc == 0) pos0++; else if (bc == 1) pos1++; else if (bc == 2) pos2++; else pos3++;
  }
}

// ---------- 8) weight bf16 conversions ----------
__global__ void k_transpose(const float* __restrict__ w2, const float* __restrict__ w3,
                            unsigned short* __restrict__ w2h, unsigned short* __restrict__ wt3h) {
  int i = blockIdx.x*256 + threadIdx.x;
  if (i < 192*128) { w2h[i] = f2bf(w2[i]); }     // [o][c] o-major, k-contiguous (B-frag native)
  if (i < 1024*256) { wt3h[i] = f2bf(w3[i]); }   // [o][c] o-major, k-contiguous
}

// ---------- 9) conv2 via bf16 MFMA: mobius A-tile + GEMM + stats + max/min ----------
// Block: 4 pairs -> 80 rows (pair-major, 20 nbrs), 192 cols, K=128 (64 mobius + 64 xc).
// 4 waves x (5 row-tiles x 3 col-tiles) MFMA 16x16x32. W in native [o][c] bf16 from global.
__global__ void __launch_bounds__(256) k_conv2m(const float* __restrict__ xp2,
    const int* __restrict__ idx2, const unsigned short* __restrict__ w2h,
    float* __restrict__ hmax2, float* __restrict__ hmin2, double* __restrict__ stats2sh) {
  __shared__ __align__(16) float Af[80*68];      // fp32 staging / epilogue D scratch
  __shared__ __align__(16) short Abf[80*136];    // bf16 A, K=128, stride 136 (uniform banks)
  __shared__ __align__(16) float xcs[4*68];
  __shared__ float s1s[80], s2s[80];
  __shared__ int nbr[80];
  int tid = threadIdx.x;
  int p0 = blockIdx.x * 4;
  int b = p0 >> 10;
  {
    int g = tid >> 6, c = tid & 63;
    xcs[g*68 + c] = xp2[(size_t)(p0 + g)*64 + c];
  }
  if (tid < 80) nbr[tid] = idx2[p0*KNN + tid];
  __syncthreads();
  // phase1: Af[r][0:64] = neighbor feat (coalesced float4)
  for (int e = tid; e < 80*16; e += 256) {
    int r = e >> 4, qq = e & 15;
    *((float4*)(Af + r*68) + qq) = *((const float4*)(xp2 + (size_t)(b*N_ + nbr[r])*64) + qq);
  }
  __syncthreads();
  // phase2: per-row mobius scalars
  if (tid < 80) {
    const float* Ar = Af + tid*68;
    const float* xc = xcs + (tid/20)*68;
    float X2 = 0.f, XY = 0.f, Y2 = 0.f;
    for (int c2 = 0; c2 < 64; c2++) {
      float f = Ar[c2], xcv = xc[c2];
      X2 = fmaf(f, f, X2); XY = fmaf(-f, xcv, XY); Y2 = fmaf(xcv, xcv, Y2);
    }
    float den = fmaxf(1.0f + 0.02f*XY + 1e-4f*X2*Y2, 1e-15f);
    s1s[tid] = (1.0f + 0.02f*XY + 0.01f*Y2) / den;
    s2s[tid] = (1.0f - 0.01f*X2) / den;
  }
  __syncthreads();
  // phase3: Abf[r][0:64] = bf16(s1*feat - s2*xc); Abf[r][64:128] = bf16(xc)
  for (int e = tid; e < 80*16; e += 256) {
    int r = e >> 4, qq = e & 15;
    float4 f = *((const float4*)(Af + r*68) + qq);
    float4 cv = *((const float4*)(xcs + (r/20)*68) + qq);
    float s1 = s1s[r], s2 = s2s[r];
    ushort4 mob, xcb;
    mob.x = f2bf(s1*f.x - s2*cv.x); mob.y = f2bf(s1*f.y - s2*cv.y);
    mob.z = f2bf(s1*f.z - s2*cv.z); mob.w = f2bf(s1*f.w - s2*cv.w);
    xcb.x = f2bf(cv.x); xcb.y = f2bf(cv.y); xcb.z = f2bf(cv.z); xcb.w = f2bf(cv.w);
    *((ushort4*)(Abf + r*136 + qq*4)) = mob;
    *((ushort4*)(Abf + r*136 + 64 + qq*4)) = xcb;
  }
  __syncthreads();
  // MFMA GEMM: per wave 48 cols x 80 rows, K=128 in 4 steps
  int wave = tid >> 6, lane = tid & 63;
  int quad = lane >> 4, lm = lane & 15;
  int colbase = wave*48;
  f32x4 acc[5][3];
  #pragma unroll
  for (int rt = 0; rt < 5; rt++)
    #pragma unroll
    for (int cj = 0; cj < 3; cj++) acc[rt][cj] = (f32x4){0.f, 0.f, 0.f, 0.f};
  #pragma unroll
  for (int kt = 0; kt < 4; kt++) {
    int k0 = kt*32 + quad*8;
    bf16x8 bf[3];
    #pragma unroll
    for (int cj = 0; cj < 3; cj++)
      bf[cj] = *((const bf16x8*)(w2h + (size_t)(colbase + cj*16 + lm)*128 + k0));
    bf16x8 af[5];
    #pragma unroll
    for (int rt = 0; rt < 5; rt++)
      af[rt] = *((const bf16x8*)(Abf + (rt*16 + lm)*136 + k0));
    #pragma unroll
    for (int rt = 0; rt < 5; rt++)
      #pragma unroll
      for (int cj = 0; cj < 3; cj++)
        acc[rt][cj] = __builtin_amdgcn_mfma_f32_16x16x32_bf16(af[rt], bf[cj], acc[rt][cj], 0, 0, 0);
  }
  // epilogue: 3 rounds over cj; D rows in Af (col' = wave*16+lm), then 64-thread scans
  for (int cj = 0; cj < 3; cj++) {
    __syncthreads();
    #pragma unroll
    for (int rt = 0; rt < 5; rt++) {
      #pragma unroll
      for (int reg = 0; reg < 4; reg++) {
        int row = rt*16 + quad*4 + reg;
        Af[row*68 + wave*16 + lm] = acc[rt][cj][reg];
      }
    }
    __syncthreads();
    if (tid < 64) {
      int o = (tid >> 4)*48 + cj*16 + (tid & 15);   // global out-channel
      float s = 0.f, s2 = 0.f;
      float mx[4], mn[4];
      #pragma unroll
      for (int g = 0; g < 4; g++) { mx[g] = -__builtin_inff(); mn[g] = __builtin_inff(); }
      int r = 0;
      #pragma unroll
      for (int g = 0; g < 4; g++) {
        #pragma unroll
        for (int kk = 0; kk < KNN; kk++, r++) {
          float h = Af[r*68 + tid];
          s += h; s2 += h*h;
          mx[g] = fmaxf(mx[g], h); mn[g] = fminf(mn[g], h);
        }
      }
      double* dst = stats2sh + ((size_t)(blockIdx.x & 63)*192 + o)*2;
      atomicAdd(dst, (double)s); atomicAdd(dst + 1, (double)s2);
      #pragma unroll
      for (int g = 0; g < 4; g++) {
        hmax2[(size_t)(p0 + g)*192 + o] = mx[g];
        hmin2[(size_t)(p0 + g)*192 + o] = mn[g];
      }
    }
  }
}

// ---------- 10) BN2 apply (writes bf16 feat) ----------
__global__ void k_bn2_apply(const float* __restrict__ hmax2, const float* __restrict__ hmin2,
                            const float* __restrict__ scale2, const float* __restrict__ shift2,
                            unsigned short* __restrict__ feat3h) {
  int e = blockIdx.x*256 + threadIdx.x;
  if (e >= NPAIR*192) return;
  int p = e / 192, o = e - p*192;
  float a = scale2[o], t = shift2[o];
  float h = (a >= 0.f) ? hmax2[e] : hmin2[e];
  feat3h[(size_t)p*256 + 64 + o] = f2bf(fmaxf(fmaf(a, h, t), 0.f));
}

// ---------- 11) conv3 via bf16 MFMA + stats + max/min over n ----------
__global__ void __launch_bounds__(256) k_conv3m(const unsigned short* __restrict__ feat3h,
   const unsigned short* __restrict__ wt3h, double* __restrict__ stats3sh,
   unsigned* __restrict__ hmax3u, unsigned* __restrict__ hmin3u) {
  __shared__ short As[64*264];   // 33792 B
  int tid = threadIdx.x;
  int mt = blockIdx.x >> 2, cb = blockIdx.x & 3;
  int rowbase = mt*64;
  int b = rowbase >> 10;
  for (int e = tid; e < 64*32; e += 256) {
    int r = e >> 5, ch = e & 31;
    *((float4*)(As + r*264 + ch*8)) =
      *((const float4*)(feat3h + (size_t)(rowbase + r)*256 + ch*8));
  }
  __syncthreads();
  int wave = tid >> 6, lane = tid & 63;
  int quad = lane >> 4, lm = lane & 15;
  int colbase = cb*256 + wave*64;
  f32x4 acc[4][4];   // [ri][cj]
  #pragma unroll
  for (int ri = 0; ri < 4; ri++)
    #pragma unroll
    for (int cj = 0; cj < 4; cj++) acc[ri][cj] = (f32x4){0.f, 0.f, 0.f, 0.f};
  for (int kt = 0; kt < 8; kt++) {
    int k0 = kt*32 + quad*8;
    bf16x8 bf[4];
    #pragma unroll
    for (int cj = 0; cj < 4; cj++)
      bf[cj] = *((const bf16x8*)(wt3h + (size_t)(colbase + cj*16 + lm)*256 + k0));
    bf16x8 af[4];
    #pragma unroll
    for (int ri = 0; ri < 4; ri++)
      af[ri] = *((const bf16x8*)(As + (ri*16 + lm)*264 + k0));
    #pragma unroll
    for (int ri = 0; ri < 4; ri++)
      #pragma unroll
      for (int cj = 0; cj < 4; cj++)
        acc[ri][cj] = __builtin_amdgcn_mfma_f32_16x16x32_bf16(af[ri], bf[cj], acc[ri][cj], 0, 0, 0);
  }
  #pragma unroll
  for (int cj = 0; cj < 4; cj++) {
    float s = 0.f, s2 = 0.f, mx = -__builtin_inff(), mn = __builtin_inff();
    #pragma unroll
    for (int ri = 0; ri < 4; ri++) {
      #pragma unroll
      for (int reg = 0; reg < 4; reg++) {
        float h = acc[ri][cj][reg];
        s += h; s2 += h*h; mx = fmaxf(mx, h); mn = fminf(mn, h);
      }
    }
    s  += __shfl_xor(s, 16);  s  += __shfl_xor(s, 32);
    s2 += __shfl_xor(s2, 16); s2 += __shfl_xor(s2, 32);
    mx = fmaxf(mx, __shfl_xor(mx, 16)); mx = fmaxf(mx, __shfl_xor(mx, 32));
    mn = fminf(mn, __shfl_xor(mn, 16)); mn = fminf(mn, __shfl_xor(mn, 32));
    if (lane < 16) {
      int col = colbase + cj*16 + lane;
      double* dst = stats3sh + ((size_t)(blockIdx.x & 63)*1024 + col)*2;
      atomicAdd(dst, (double)s);
      atomicAdd(dst + 1, (double)s2);
      atomicMax(hmax3u + b*1024 + col, fkey(mx));
      atomicMin(hmin3u + b*1024 + col, fkey(mn));
    }
  }
}

// ---------- 12) head ----------
__device__ float blk_reduce(float v, float* red, int tid) {
  red[tid] = v; __syncthreads();
  for (int st = 128; st > 0; st >>= 1) {
    if (tid < st) red[tid] += red[tid + st];
    __syncthreads();
  }
  float r = red[0]; __syncthreads();
  return r;
}

__global__ void __launch_bounds__(256) k_head(const unsigned* __restrict__ hmax3u, const unsigned* __restrict__ hmin3u,
    const float* __restrict__ scale3, const float* __restrict__ shift3,
    const float* __restrict__ fc1w, const float* __restrict__ fc1b,
    const float* __restrict__ ln1g, const float* __restrict__ ln1b,
    const float* __restrict__ fc2w, const float* __restrict__ fc2b,
    const float* __restrict__ ln2g, const float* __restrict__ ln2b,
    const float* __restrict__ outw, const float* __restrict__ outb,
    float* __restrict__ out) {
  __shared__ __align__(16) float V[1024];
  __shared__ __align__(16) float H1[512];
  __shared__ __align__(16) float H2[256];
  __shared__ float red[256];
  int b = blockIdx.x, tid = threadIdx.x;
  for (int o = tid; o < 1024; o += 256) {
    float a = scale3[o];
    unsigned u = (a >= 0.f) ? hmax3u[b*1024 + o] : hmin3u[b*1024 + o];
    float h = fkeyinv(u);
    V[o] = fmaxf(fmaf(a, h, shift3[o]), 0.f);
  }
  __syncthreads();
  float h1v[2];
  #pragma unroll
  for (int ii = 0; ii < 2; ii++) {
    int o = tid + ii*256;
    const float4* wr = (const float4*)(fc1w + (size_t)o*1024);
    float s = 0.f;
    for (int c4 = 0; c4 < 256; c4++) {
      float4 w = wr[c4]; float4 vv = ((const float4*)V)[c4];
      s = fmaf(w.x, vv.x, s); s = fmaf(w.y, vv.y, s);
      s = fmaf(w.z, vv.z, s); s = fmaf(w.w, vv.w, s);
    }
    h1v[ii] = s + fc1b[o];
  }
  float s = h1v[0] + h1v[1];
  float s2 = h1v[0]*h1v[0] + h1v[1]*h1v[1];
  s = blk_reduce(s, red, tid);
  s2 = blk_reduce(s2, red, tid);
  float m = s / 512.f;
  float var = s2 / 512.f - m*m;
  float inv = 1.0f / sqrtf(var + 1e-5f);
  #pragma unroll
  for (int ii = 0; ii < 2; ii++) {
    int o = tid + ii*256;
    H1[o] = fmaxf((h1v[ii] - m)*inv*ln1g[o] + ln1b[o], 0.f);
  }
  __syncthreads();
  float h2v;
  {
    const float4* wr = (const float4*)(fc2w + (size_t)tid*512);
    float t = 0.f;
    for (int c4 = 0; c4 < 128; c4++) {
      float4 w = wr[c4]; float4 vv = ((const float4*)H1)[c4];
      t = fmaf(w.x, vv.x, t); t = fmaf(w.y, vv.y, t);
      t = fmaf(w.z, vv.z, t); t = fmaf(w.w, vv.w, t);
    }
    h2v = t + fc2b[tid];
  }
  float ss = blk_reduce(h2v, red, tid);
  float ss2 = blk_reduce(h2v*h2v, red, tid);
  float m2 = ss / 256.f;
  float var2 = ss2 / 256.f - m2*m2;
  float inv2 = 1.0f / sqrtf(var2 + 1e-5f);
  H2[tid] = fmaxf((h2v - m2)*inv2*ln2g[tid] + ln2b[tid], 0.f);
  __syncthreads();
  if (tid < 40) {
    const float4* wr = (const float4*)(outw + (size_t)tid*256);
    float t = 0.f;
    for (int c4 = 0; c4 < 64; c4++) {
      float4 w = wr[c4]; float4 vv = ((const float4*)H2)[c4];
      t = fmaf(w.x, vv.x, t); t = fmaf(w.y, vv.y, t);
      t = fmaf(w.z, vv.z, t); t = fmaf(w.w, vv.w, t);
    }
    red[tid] = t + outb[tid];
  }
  __syncthreads();
  if (tid == 0) {
    float mx = -__builtin_inff();
    for (int i2 = 0; i2 < 40; i2++) mx = fmaxf(mx, red[i2]);
    float se = 0.f;
    for (int i2 = 0; i2 < 40; i2++) se += expf(red[i2] - mx);
    float lse = mx + logf(se);
    for (int i2 = 0; i2 < 40; i2++) out[b*40 + i2] = red[i2] - lse;
  }
}

extern "C" void kernel_launch(void* const* d_in, const int* in_sizes, int n_in,
                              void* d_out, int out_size, void* d_ws, size_t ws_size,
                              hipStream_t stream) {
  (void)in_sizes; (void)n_in; (void)out_size; (void)ws_size;
  const float* x    = (const float*)d_in[0];
  const float* w1   = (const float*)d_in[1];
  const float* bn1g = (const float*)d_in[2];
  const float* bn1b = (const float*)d_in[3];
  const float* w2   = (const float*)d_in[4];
  const float* bn2g = (const float*)d_in[5];
  const float* bn2b = (const float*)d_in[6];
  const float* w3   = (const float*)d_in[7];
  const float* bn3g = (const float*)d_in[8];
  const float* bn3b = (const float*)d_in[9];
  const float* fc1w = (const float*)d_in[10];
  const float* fc1b = (const float*)d_in[11];
  const float* ln1g = (const float*)d_in[12];
  const float* ln1b = (const float*)d_in[13];
  const float* fc2w = (const float*)d_in[14];
  const float* fc2b = (const float*)d_in[15];
  const float* ln2g = (const float*)d_in[16];
  const float* ln2b = (const float*)d_in[17];
  const float* outw = (const float*)d_in[18];
  const float* outb = (const float*)d_in[19];
  float* out = (float*)d_out;

  float* ws = (float*)d_ws;
  size_t off = 0;
  float* xp1   = ws + off; off += 49152;
  int*   idx1  = (int*)(ws + off); off += 327680;
  float* hmax1 = ws + off; off += 1048576;
  float* hmin1 = ws + off; off += 1048576;
  unsigned short* feat3h = (unsigned short*)(ws + off); off += 2097152;  // 16384x256 bf16
  float* xp2   = ws + off; off += 1048576;
  float* hmax2 = ws + off; off += 3145728;   // also pdpart (knn partials)
  float* hmin2 = ws + off; off += 3145728;   // also idxpart
  int*   idx2  = (int*)(ws + off); off += 327680;
  unsigned short* w2h = (unsigned short*)(ws + off); off += 24576;       // 192x128 bf16
  unsigned short* wt3h = (unsigned short*)(ws + off); off += 131072;     // 1024x256 bf16
  float* x1T   = ws + off; off += 1048576;   // (b,c,n) transposed x1
  float* xx1   = ws + off; off += 16384;     // |x1|^2 per point
  float* scale1 = ws + off; off += 64;
  float* shift1 = ws + off; off += 64;
  float* scale2 = ws + off; off += 192;
  float* shift2 = ws + off; off += 192;
  float* scale3 = ws + off; off += 1024;
  float* shift3 = ws + off; off += 1024;
  double* stats1sh = (double*)(ws + off);           // 64*64*2 doubles
  double* stats2sh = stats1sh + 64*64*2;            // 64*192*2 doubles
  double* stats3sh = stats2sh + 64*192*2;           // 64*1024*2 doubles
  unsigned* hmax3u = (unsigned*)(stats3sh + (size_t)64*1024*2);  // 16384 u32
  unsigned* hmin3u = hmax3u + 16384;                             // 16384 u32
  float* pdpart = hmax2;
  int*   idxpart = (int*)hmin2;

  size_t zero_bytes = ((size_t)64*64*2 + (size_t)64*192*2 + (size_t)64*1024*2)*8 + (size_t)16384*4;
  hipMemsetAsync(stats1sh, 0, zero_bytes, stream);
  hipMemsetAsync(hmin3u, 0xFF, (size_t)16384*4, stream);

  k_e2p1<<<64, 256, 0, stream>>>(x, xp1);
  k_knn1_part<<<256, 256, 0, stream>>>(x, pdpart, idxpart);
  k_knn2_merge<<<64, 256, 0, stream>>>(pdpart, idxpart, idx1);
  k_transpose<<<1024, 256, 0, stream>>>(w2, w3, w2h, wt3h);
  k_conv1<<<1024, 256, 0, stream>>>(xp1, idx1, w1, hmax1, hmin1, stats1sh);
  k_bn_reduce<<<1, 64, 0, stream>>>(stats1sh, 64, 64, 327680.0, bn1g, bn1b, scale1, shift1);
  k_bn1_apply<<<4096, 256, 0, stream>>>(hmax1, hmin1, scale1, shift1, feat3h, xp2, x1T, xx1);
  k_knn2g<<<512, 256, 0, stream>>>(x1T, xx1, pdpart, idxpart);
  k_knn2_merge<<<64, 256, 0, stream>>>(pdpart, idxpart, idx2);
  k_conv2m<<<4096, 256, 0, stream>>>(xp2, idx2, w2h, hmax2, hmin2, stats2sh);
  k_bn_reduce<<<1, 192, 0, stream>>>(stats2sh, 64, 192, 327680.0, bn2g, bn2b, scale2, shift2);
  k_bn2_apply<<<12288, 256, 0, stream>>>(hmax2, hmin2, scale2, shift2, feat3h);
  k_conv3m<<<1024, 256, 0, stream>>>(feat3h, wt3h, stats3sh, hmax3u, hmin3u);
  k_bn_reduce<<<4, 256, 0, stream>>>(stats3sh, 64, 1024, 16384.0, bn3g, bn3b, scale3, shift3);
  k_head<<<16, 256, 0, stream>>>(hmax3u, hmin3u, scale3, shift3,
                                 fc1w, fc1b, ln1g, ln1b,
                                 fc2w, fc2b, ln2g, ln2b,
                                 outw, outb, out);
}

// Round 8
// 636.465 us; speedup vs baseline: 1.8179x; 1.0809x over previous
//
#include <hip/hip_runtime.h>
#include <math.h>

#define B_ 16
#define N_ 1024
#define KNN 20
#define NPAIR (B_*N_)

typedef __attribute__((ext_vector_type(8))) short bf16x8;
typedef __attribute__((ext_vector_type(4))) float f32x4;

// ---------- helpers ----------
__device__ __forceinline__ unsigned fkey(float f) {
  unsigned u = __float_as_uint(f);
  return (u & 0x80000000u) ? ~u : (u | 0x80000000u);
}
__device__ __forceinline__ float fkeyinv(unsigned u) {
  unsigned b = (u & 0x80000000u) ? (u ^ 0x80000000u) : ~u;
  return __uint_as_float(b);
}
__device__ __forceinline__ unsigned short f2bf(float x) {  // RNE float->bf16
  unsigned u = __float_as_uint(x);
  unsigned r = (u + 0x7FFFu + ((u >> 16) & 1u)) >> 16;
  return (unsigned short)r;
}

// Branchless (cndmask-chain) insertion into a descending sorted top-20.
__device__ __forceinline__ void topk_insert(float (&pdl)[KNN], int (&idl)[KNN], float d, int j) {
  pdl[KNN-1] = d; idl[KNN-1] = j;
  #pragma unroll
  for (int i = KNN-1; i > 0; i--) {
    float a = pdl[i-1], bv = pdl[i];
    int ai = idl[i-1], bi = idl[i];
    bool sw = bv > a;
    pdl[i-1] = sw ? bv : a;   pdl[i] = sw ? a  : bv;
    idl[i-1] = sw ? bi : ai;  idl[i] = sw ? ai : bi;
  }
}

// ---------- 1) e2p of raw points ----------
__global__ void k_e2p1(const float* __restrict__ x, float* __restrict__ xp1) {
  int p = blockIdx.x * 256 + threadIdx.x;
  if (p >= NPAIR) return;
  float a0 = x[p*3+0], a1 = x[p*3+1], a2 = x[p*3+2];
  float n = sqrtf(a0*a0 + a1*a1 + a2*a2);
  n = fmaxf(n, 1e-15f);
  float th = tanhf(0.1f * n);
  float sc = th / (0.1f * n);
  float ny = fmaxf(th * 10.0f, 1e-15f);
  float mxn = (1.0f - 4e-3f) / 0.1f;
  if (ny > mxn) sc *= mxn / ny;
  xp1[p*3+0] = sc*a0; xp1[p*3+1] = sc*a1; xp1[p*3+2] = sc*a2;
}

// ---------- 2) knn on raw 3-d points: 8-way candidate split ----------
// grid: b(16) x rowchunk(4, 256 q) x colchunk(8, 128 cand) = 512 blocks
__global__ void __launch_bounds__(256) k_knn1_part(const float* __restrict__ x,
        float* __restrict__ pdpart, int* __restrict__ idxpart) {
  __shared__ float P[N_*3];
  __shared__ float XX[N_];
  int blk = blockIdx.x;
  int b = blk >> 5, rc = (blk >> 3) & 3, cc = blk & 7;
  const float* xb = x + b*N_*3;
  for (int e = threadIdx.x; e < N_*3; e += 256) P[e] = xb[e];
  __syncthreads();
  for (int j = threadIdx.x; j < N_; j += 256) {
    float q0 = P[j*3], q1 = P[j*3+1], q2 = P[j*3+2];
    XX[j] = q0*q0 + q1*q1 + q2*q2;
  }
  __syncthreads();
  int r = rc*256 + threadIdx.x;
  float q0 = P[r*3], q1 = P[r*3+1], q2 = P[r*3+2];
  float xxq = XX[r];
  float pdl[KNN]; int idl[KNN];
  #pragma unroll
  for (int i = 0; i < KNN; i++) { pdl[i] = -__builtin_inff(); idl[i] = 0; }
  int cbase = cc*128;
  for (int jj = 0; jj < 128; jj++) {
    int j = cbase + jj;
    float dot = q0*P[j*3] + q1*P[j*3+1] + q2*P[j*3+2];
    float d = 2.0f*dot - xxq - XX[j];
    if (d > pdl[KNN-1]) topk_insert(pdl, idl, d, j);
  }
  int p = b*N_ + r;
  float* pe = pdpart + (size_t)p*160 + cc*20;
  int* ie = idxpart + (size_t)p*160 + cc*20;
  #pragma unroll
  for (int i = 0; i < KNN; i++) { pe[i] = pdl[i]; ie[i] = idl[i]; }
}

// ---------- 3) conv1 fused ----------
__global__ void __launch_bounds__(256) k_conv1(const float* __restrict__ xp1, const int* __restrict__ idx1,
                        const float* __restrict__ w1, float* __restrict__ hmax1,
                        float* __restrict__ hmin1, double* __restrict__ stats1sh) {
  __shared__ float F[4][KNN][6];
  __shared__ float red[4][64][2];
  int g = threadIdx.x >> 6, lane = threadIdx.x & 63;
  float w[6];
  #pragma unroll
  for (int c = 0; c < 6; c++) w[c] = w1[lane*6 + c];
  float sum = 0.f, sumsq = 0.f;
  int pbase = blockIdx.x * 16;
  for (int it = 0; it < 4; ++it) {
    int p = pbase + it*4 + g;
    if (lane < KNN) {
      int nb = idx1[p*KNN + lane];
      int bb = p >> 10;
      const float* xc = xp1 + p*3;
      const float* ft = xp1 + (bb*N_ + nb)*3;
      float x0 = ft[0], x1 = ft[1], x2v = ft[2];
      float c0 = xc[0], c1 = xc[1], c2 = xc[2];
      float X2 = x0*x0 + x1*x1 + x2v*x2v;
      float Y2 = c0*c0 + c1*c1 + c2*c2;
      float XY = -(x0*c0 + x1*c1 + x2v*c2);
      float den = fmaxf(1.0f + 0.02f*XY + 1e-4f*X2*Y2, 1e-15f);
      float s1 = (1.0f + 0.02f*XY + 0.01f*Y2) / den;
      float s2 = (1.0f - 0.01f*X2) / den;
      F[g][lane][0] = s1*x0 - s2*c0;
      F[g][lane][1] = s1*x1 - s2*c1;
      F[g][lane][2] = s1*x2v - s2*c2;
      F[g][lane][3] = c0; F[g][lane][4] = c1; F[g][lane][5] = c2;
    }
    __syncthreads();
    float mx = -__builtin_inff(), mn = __builtin_inff();
    for (int k = 0; k < KNN; k++) {
      float h = 0.f;
      #pragma unroll
      for (int c = 0; c < 6; c++) h = fmaf(w[c], F[g][k][c], h);
      mx = fmaxf(mx, h); mn = fminf(mn, h);
      sum += h; sumsq += h*h;
    }
    hmax1[p*64 + lane] = mx;
    hmin1[p*64 + lane] = mn;
    __syncthreads();
  }
  red[g][lane][0] = sum; red[g][lane][1] = sumsq;
  __syncthreads();
  if (g == 0) {
    float s  = red[0][lane][0] + red[1][lane][0] + red[2][lane][0] + red[3][lane][0];
    float s2 = red[0][lane][1] + red[1][lane][1] + red[2][lane][1] + red[3][lane][1];
    double* dst = stats1sh + ((size_t)(blockIdx.x & 63)*64 + lane)*2;
    atomicAdd(dst, (double)s);
    atomicAdd(dst + 1, (double)s2);
  }
}

// ---------- BN stat reduce ----------
__global__ void k_bn_reduce(const double* __restrict__ sh, int nsh, int nch, double cnt,
                            const float* __restrict__ g, const float* __restrict__ bb,
                            float* __restrict__ scale, float* __restrict__ shift) {
  int o = blockIdx.x * blockDim.x + threadIdx.x;
  if (o >= nch) return;
  double s = 0.0, s2 = 0.0;
  for (int i = 0; i < nsh; i++) {
    s  += sh[((size_t)i*nch + o)*2];
    s2 += sh[((size_t)i*nch + o)*2 + 1];
  }
  double m = s / cnt;
  double v = s2 / cnt - m*m;
  float a = g[o] / sqrtf((float)v + 1e-5f);
  scale[o] = a;
  shift[o] = bb[o] - a * (float)m;
}

// ---------- 5) BN1 apply + relu + e2p of x1 + transposed copy + |x1|^2 ----------
__global__ void __launch_bounds__(256) k_bn1_apply(const float* __restrict__ hmax1, const float* __restrict__ hmin1,
                            const float* __restrict__ scale1, const float* __restrict__ shift1,
                            unsigned short* __restrict__ feat3h, float* __restrict__ xp2,
                            float* __restrict__ x1T, float* __restrict__ xx1) {
  int p = blockIdx.x*4 + (threadIdx.x >> 6);
  int c = threadIdx.x & 63;
  float a = scale1[c], t = shift1[c];
  float h = (a >= 0.f) ? hmax1[p*64 + c] : hmin1[p*64 + c];
  float x1 = fmaxf(fmaf(a, h, t), 0.f);
  feat3h[(size_t)p*256 + c] = f2bf(x1);
  int b = p >> 10, n = p & 1023;
  x1T[((size_t)(b*64 + c))*1024 + n] = x1;
  float n2 = x1*x1;
  #pragma unroll
  for (int off = 32; off > 0; off >>= 1) n2 += __shfl_xor(n2, off);
  if (c == 0) xx1[p] = n2;
  float n1 = fmaxf(sqrtf(n2), 1e-15f);
  float th = tanhf(0.1f * n1);
  float sc = th / (0.1f * n1);
  float ny = fmaxf(th * 10.0f, 1e-15f);
  float mxn = (1.0f - 4e-3f) / 0.1f;
  if (ny > mxn) sc *= mxn / ny;
  xp2[p*64 + c] = sc * x1;
}

// ---------- 6) knn2 v3: GEMM-tiled distances, all-wave selection, in-block merge ----------
// grid: b(16) x qchunk(16, 64 q) x cchunk(4, 256 cand) = 1024 blocks, 256 thr.
// LDS: As[64k][68q] (staged once) + BsD[64k][64c] (Bs, overwritten by D each subtile).
// Selection: lane = query, wave w owns candidate quarter; block merge 4x20 -> cc-partial.
__global__ void __launch_bounds__(256) k_knn2g(const float* __restrict__ x1T,
        const float* __restrict__ xx1,
        float* __restrict__ pdpart, int* __restrict__ idxpart) {
  __shared__ __align__(16) float SM[8448];   // As @0 (64x68), BsD @4352 (64x64)
  float* As = SM;
  float* BsD = SM + 4352;
  int tid = threadIdx.x;
  int blk = blockIdx.x;
  int b = blk >> 6, qc = (blk >> 2) & 15, cc = blk & 3;
  int qbase = qc*64, ccbase = cc*256;
  int tx = tid & 15, ty = tid >> 4;
  int wave = tid >> 6, lane = tid & 63;
  // stage As once: 64 k x 64 q
  #pragma unroll
  for (int r = 0; r < 4; r++) {
    int e = tid + r*256;
    int k = e >> 4, qf = e & 15;
    *((float4*)(As + k*68 + qf*4)) =
      *((const float4*)(x1T + ((size_t)(b*64 + k))*1024 + qbase + qf*4));
  }
  float pdl[KNN]; int idl[KNN];
  #pragma unroll
  for (int i = 0; i < KNN; i++) { pdl[i] = -__builtin_inff(); idl[i] = 0; }
  int cq = lane + (lane >> 2);     // selection swizzle offset for this query

  for (int st = 0; st < 4; ++st) {
    int cb0 = ccbase + st*64;
    __syncthreads();    // previous selection done (D dead); As ready (st=0)
    #pragma unroll
    for (int r = 0; r < 4; r++) {
      int e = tid + r*256;
      int k = e >> 4, cf = e & 15;
      *((float4*)(BsD + k*64 + cf*4)) =
        *((const float4*)(x1T + ((size_t)(b*64 + k))*1024 + cb0 + cf*4));
    }
    float4 xxc = *((const float4*)(xx1 + b*1024 + cb0 + ty*4));
    __syncthreads();
    float acc[4][4];
    #pragma unroll
    for (int i = 0; i < 4; i++)
      #pragma unroll
      for (int j = 0; j < 4; j++) acc[i][j] = 0.f;
    #pragma unroll 4
    for (int k = 0; k < 64; k++) {
      float4 a4 = *((const float4*)(As + k*68 + tx*4));
      float4 b4 = *((const float4*)(BsD + k*64 + ty*4));
      float av[4] = {a4.x, a4.y, a4.z, a4.w};
      float bw[4] = {b4.x, b4.y, b4.z, b4.w};
      #pragma unroll
      for (int i = 0; i < 4; i++)
        #pragma unroll
        for (int j = 0; j < 4; j++) acc[i][j] = fmaf(av[i], bw[j], acc[i][j]);
    }
    __syncthreads();    // all waves done reading Bs
    float xxv[4] = {xxc.x, xxc.y, xxc.z, xxc.w};
    #pragma unroll
    for (int i = 0; i < 4; i++) {
      int q = tx*4 + i;
      #pragma unroll
      for (int j = 0; j < 4; j++) {
        int c = ty*4 + j;
        BsD[q*64 + ((c + q + (q >> 2)) & 63)] = 2.0f*acc[i][j] - xxv[j];
      }
    }
    __syncthreads();
    // selection: lane = query; wave w scans candidates [w*16, w*16+16)
    #pragma unroll
    for (int j = 0; j < 16; j++) {
      int c = wave*16 + j;
      float d = BsD[lane*64 + ((c + cq) & 63)];
      if (d > pdl[KNN-1]) topk_insert(pdl, idl, d, cb0 + c);
    }
  }
  __syncthreads();
  // ---- block merge: 4 wave-partials -> exact top-20 of this cc chunk ----
  // LDS layout (stride 21): L0pd@0 L0id@1344 L1pd@2688 L1id@4032 Mpd@5376 Mid@6720
  float* L0pd = SM;            int* L0id = (int*)(SM + 1344);
  float* L1pd = SM + 2688;     int* L1id = (int*)(SM + 4032);
  float* Mpd  = SM + 5376;     int* Mid  = (int*)(SM + 6720);
  if (wave == 0) {
    #pragma unroll
    for (int i = 0; i < KNN; i++) { L0pd[lane*21 + i] = pdl[i]; L0id[lane*21 + i] = idl[i]; }
  } else if (wave == 1) {
    #pragma unroll
    for (int i = 0; i < KNN; i++) { L1pd[lane*21 + i] = pdl[i]; L1id[lane*21 + i] = idl[i]; }
  }
  __syncthreads();
  if (tid < 64) {            // merge L0,L1 -> M
    int ia = 0, ib = 0;
    for (int t = 0; t < KNN; t++) {
      float pa = L0pd[tid*21 + ia], pb = L1pd[tid*21 + ib];
      int xa = L0id[tid*21 + ia], xb = L1id[tid*21 + ib];
      bool ta = (pa > pb) || (pa == pb && xa < xb);
      Mpd[tid*21 + t] = ta ? pa : pb;
      Mid[tid*21 + t] = ta ? xa : xb;
      if (ta) ia++; else ib++;
    }
  }
  __syncthreads();
  if (wave == 2) {
    #pragma unroll
    for (int i = 0; i < KNN; i++) { L0pd[lane*21 + i] = pdl[i]; L0id[lane*21 + i] = idl[i]; }
  } else if (wave == 3) {
    #pragma unroll
    for (int i = 0; i < KNN; i++) { L1pd[lane*21 + i] = pdl[i]; L1id[lane*21 + i] = idl[i]; }
  }
  __syncthreads();
  if (tid < 64) {            // 3-way merge M, L0(w2), L1(w3) -> global cc-partial
    int p = b*N_ + qbase + tid;
    float* pe = pdpart + (size_t)p*80 + cc*20;
    int* ie = idxpart + (size_t)p*80 + cc*20;
    int ia = 0, ib = 0, im = 0;
    for (int t = 0; t < KNN; t++) {
      float pa = L0pd[tid*21 + ia], pb = L1pd[tid*21 + ib], pm = Mpd[tid*21 + im];
      int xa = L0id[tid*21 + ia], xb = L1id[tid*21 + ib], xm = Mid[tid*21 + im];
      float bp = pm; int bx = xm; int sel = 2;
      if (pa > bp || (pa == bp && xa < bx)) { bp = pa; bx = xa; sel = 0; }
      if (pb > bp || (pb == bp && xb < bx)) { bp = pb; bx = xb; sel = 1; }
      pe[t] = bp; ie[t] = bx;
      if (sel == 0) ia++; else if (sel == 1) ib++; else im++;
    }
  }
}

// ---------- 7) generic merge of NCH sorted top-20 chunks ----------
template<int NCH>
__global__ void k_knn_merge(const float* __restrict__ pdpart, const int* __restrict__ idxpart,
                            int* __restrict__ idxo) {
  int p = blockIdx.x*256 + threadIdx.x;
  if (p >= NPAIR) return;
  const float* pe = pdpart + (size_t)p*(NCH*20);
  const int* ie = idxpart + (size_t)p*(NCH*20);
  int pos[NCH];
  #pragma unroll
  for (int c = 0; c < NCH; c++) pos[c] = 0;
  int* outp = idxo + p*KNN;
  for (int t = 0; t < KNN; t++) {
    float best = -__builtin_inff(); int bi = 0x7FFFFFFF; int bc = 0;
    #pragma unroll
    for (int c = 0; c < NCH; c++) {
      if (pos[c] < KNN) {
        float pv = pe[c*20 + pos[c]]; int iv = ie[c*20 + pos[c]];
        if (pv > best || (pv == best && iv < bi)) { best = pv; bi = iv; bc = c; }
      }
    }
    outp[t] = bi;
    #pragma unroll
    for (int c = 0; c < NCH; c++) if (bc == c) pos[c]++;
  }
}

// ---------- 8) weight bf16 conversions ----------
__global__ void k_transpose(const float* __restrict__ w2, const float* __restrict__ w3,
                            unsigned short* __restrict__ w2h, unsigned short* __restrict__ wt3h) {
  int i = blockIdx.x*256 + threadIdx.x;
  if (i < 192*128) { w2h[i] = f2bf(w2[i]); }
  if (i < 1024*256) { wt3h[i] = f2bf(w3[i]); }
}

// ---------- 9) conv2 via bf16 MFMA ----------
__global__ void __launch_bounds__(256) k_conv2m(const float* __restrict__ xp2,
    const int* __restrict__ idx2, const unsigned short* __restrict__ w2h,
    float* __restrict__ hmax2, float* __restrict__ hmin2, double* __restrict__ stats2sh) {
  __shared__ __align__(16) float Af[80*68];
  __shared__ __align__(16) short Abf[80*136];
  __shared__ __align__(16) float xcs[4*68];
  __shared__ float s1s[80], s2s[80];
  __shared__ int nbr[80];
  int tid = threadIdx.x;
  int p0 = blockIdx.x * 4;
  int b = p0 >> 10;
  {
    int g = tid >> 6, c = tid & 63;
    xcs[g*68 + c] = xp2[(size_t)(p0 + g)*64 + c];
  }
  if (tid < 80) nbr[tid] = idx2[p0*KNN + tid];
  __syncthreads();
  for (int e = tid; e < 80*16; e += 256) {
    int r = e >> 4, qq = e & 15;
    *((float4*)(Af + r*68) + qq) = *((const float4*)(xp2 + (size_t)(b*N_ + nbr[r])*64) + qq);
  }
  __syncthreads();
  if (tid < 80) {
    const float* Ar = Af + tid*68;
    const float* xc = xcs + (tid/20)*68;
    float X2 = 0.f, XY = 0.f, Y2 = 0.f;
    for (int c2 = 0; c2 < 64; c2++) {
      float f = Ar[c2], xcv = xc[c2];
      X2 = fmaf(f, f, X2); XY = fmaf(-f, xcv, XY); Y2 = fmaf(xcv, xcv, Y2);
    }
    float den = fmaxf(1.0f + 0.02f*XY + 1e-4f*X2*Y2, 1e-15f);
    s1s[tid] = (1.0f + 0.02f*XY + 0.01f*Y2) / den;
    s2s[tid] = (1.0f - 0.01f*X2) / den;
  }
  __syncthreads();
  for (int e = tid; e < 80*16; e += 256) {
    int r = e >> 4, qq = e & 15;
    float4 f = *((const float4*)(Af + r*68) + qq);
    float4 cv = *((const float4*)(xcs + (r/20)*68) + qq);
    float s1 = s1s[r], s2 = s2s[r];
    ushort4 mob, xcb;
    mob.x = f2bf(s1*f.x - s2*cv.x); mob.y = f2bf(s1*f.y - s2*cv.y);
    mob.z = f2bf(s1*f.z - s2*cv.z); mob.w = f2bf(s1*f.w - s2*cv.w);
    xcb.x = f2bf(cv.x); xcb.y = f2bf(cv.y); xcb.z = f2bf(cv.z); xcb.w = f2bf(cv.w);
    *((ushort4*)(Abf + r*136 + qq*4)) = mob;
    *((ushort4*)(Abf + r*136 + 64 + qq*4)) = xcb;
  }
  __syncthreads();
  int wave = tid >> 6, lane = tid & 63;
  int quad = lane >> 4, lm = lane & 15;
  int colbase = wave*48;
  f32x4 acc[5][3];
  #pragma unroll
  for (int rt = 0; rt < 5; rt++)
    #pragma unroll
    for (int cj = 0; cj < 3; cj++) acc[rt][cj] = (f32x4){0.f, 0.f, 0.f, 0.f};
  #pragma unroll
  for (int kt = 0; kt < 4; kt++) {
    int k0 = kt*32 + quad*8;
    bf16x8 bf[3];
    #pragma unroll
    for (int cj = 0; cj < 3; cj++)
      bf[cj] = *((const bf16x8*)(w2h + (size_t)(colbase + cj*16 + lm)*128 + k0));
    bf16x8 af[5];
    #pragma unroll
    for (int rt = 0; rt < 5; rt++)
      af[rt] = *((const bf16x8*)(Abf + (rt*16 + lm)*136 + k0));
    #pragma unroll
    for (int rt = 0; rt < 5; rt++)
      #pragma unroll
      for (int cj = 0; cj < 3; cj++)
        acc[rt][cj] = __builtin_amdgcn_mfma_f32_16x16x32_bf16(af[rt], bf[cj], acc[rt][cj], 0, 0, 0);
  }
  for (int cj = 0; cj < 3; cj++) {
    __syncthreads();
    #pragma unroll
    for (int rt = 0; rt < 5; rt++) {
      #pragma unroll
      for (int reg = 0; reg < 4; reg++) {
        int row = rt*16 + quad*4 + reg;
        Af[row*68 + wave*16 + lm] = acc[rt][cj][reg];
      }
    }
    __syncthreads();
    if (tid < 64) {
      int o = (tid >> 4)*48 + cj*16 + (tid & 15);
      float s = 0.f, s2 = 0.f;
      float mx[4], mn[4];
      #pragma unroll
      for (int g = 0; g < 4; g++) { mx[g] = -__builtin_inff(); mn[g] = __builtin_inff(); }
      int r = 0;
      #pragma unroll
      for (int g = 0; g < 4; g++) {
        #pragma unroll
        for (int kk = 0; kk < KNN; kk++, r++) {
          float h = Af[r*68 + tid];
          s += h; s2 += h*h;
          mx[g] = fmaxf(mx[g], h); mn[g] = fminf(mn[g], h);
        }
      }
      double* dst = stats2sh + ((size_t)(blockIdx.x & 63)*192 + o)*2;
      atomicAdd(dst, (double)s); atomicAdd(dst + 1, (double)s2);
      #pragma unroll
      for (int g = 0; g < 4; g++) {
        hmax2[(size_t)(p0 + g)*192 + o] = mx[g];
        hmin2[(size_t)(p0 + g)*192 + o] = mn[g];
      }
    }
  }
}

// ---------- 10) BN2 apply (writes bf16 feat) ----------
__global__ void k_bn2_apply(const float* __restrict__ hmax2, const float* __restrict__ hmin2,
                            const float* __restrict__ scale2, const float* __restrict__ shift2,
                            unsigned short* __restrict__ feat3h) {
  int e = blockIdx.x*256 + threadIdx.x;
  if (e >= NPAIR*192) return;
  int p = e / 192, o = e - p*192;
  float a = scale2[o], t = shift2[o];
  float h = (a >= 0.f) ? hmax2[e] : hmin2[e];
  feat3h[(size_t)p*256 + 64 + o] = f2bf(fmaxf(fmaf(a, h, t), 0.f));
}

// ---------- 11) conv3 via bf16 MFMA ----------
__global__ void __launch_bounds__(256) k_conv3m(const unsigned short* __restrict__ feat3h,
   const unsigned short* __restrict__ wt3h, double* __restrict__ stats3sh,
   unsigned* __restrict__ hmax3u, unsigned* __restrict__ hmin3u) {
  __shared__ short As[64*264];
  int tid = threadIdx.x;
  int mt = blockIdx.x >> 2, cb = blockIdx.x & 3;
  int rowbase = mt*64;
  int b = rowbase >> 10;
  for (int e = tid; e < 64*32; e += 256) {
    int r = e >> 5, ch = e & 31;
    *((float4*)(As + r*264 + ch*8)) =
      *((const float4*)(feat3h + (size_t)(rowbase + r)*256 + ch*8));
  }
  __syncthreads();
  int wave = tid >> 6, lane = tid & 63;
  int quad = lane >> 4, lm = lane & 15;
  int colbase = cb*256 + wave*64;
  f32x4 acc[4][4];
  #pragma unroll
  for (int ri = 0; ri < 4; ri++)
    #pragma unroll
    for (int cj = 0; cj < 4; cj++) acc[ri][cj] = (f32x4){0.f, 0.f, 0.f, 0.f};
  for (int kt = 0; kt < 8; kt++) {
    int k0 = kt*32 + quad*8;
    bf16x8 bf[4];
    #pragma unroll
    for (int cj = 0; cj < 4; cj++)
      bf[cj] = *((const bf16x8*)(wt3h + (size_t)(colbase + cj*16 + lm)*256 + k0));
    bf16x8 af[4];
    #pragma unroll
    for (int ri = 0; ri < 4; ri++)
      af[ri] = *((const bf16x8*)(As + (ri*16 + lm)*264 + k0));
    #pragma unroll
    for (int ri = 0; ri < 4; ri++)
      #pragma unroll
      for (int cj = 0; cj < 4; cj++)
        acc[ri][cj] = __builtin_amdgcn_mfma_f32_16x16x32_bf16(af[ri], bf[cj], acc[ri][cj], 0, 0, 0);
  }
  #pragma unroll
  for (int cj = 0; cj < 4; cj++) {
    float s = 0.f, s2 = 0.f, mx = -__builtin_inff(), mn = __builtin_inff();
    #pragma unroll
    for (int ri = 0; ri < 4; ri++) {
      #pragma unroll
      for (int reg = 0; reg < 4; reg++) {
        float h = acc[ri][cj][reg];
        s += h; s2 += h*h; mx = fmaxf(mx, h); mn = fminf(mn, h);
      }
    }
    s  += __shfl_xor(s, 16);  s  += __shfl_xor(s, 32);
    s2 += __shfl_xor(s2, 16); s2 += __shfl_xor(s2, 32);
    mx = fmaxf(mx, __shfl_xor(mx, 16)); mx = fmaxf(mx, __shfl_xor(mx, 32));
    mn = fminf(mn, __shfl_xor(mn, 16)); mn = fminf(mn, __shfl_xor(mn, 32));
    if (lane < 16) {
      int col = colbase + cj*16 + lane;
      double* dst = stats3sh + ((size_t)(blockIdx.x & 63)*1024 + col)*2;
      atomicAdd(dst, (double)s);
      atomicAdd(dst + 1, (double)s2);
      atomicMax(hmax3u + b*1024 + col, fkey(mx));
      atomicMin(hmin3u + b*1024 + col, fkey(mn));
    }
  }
}

// ---------- 12) head ----------
__device__ float blk_reduce(float v, float* red, int tid) {
  red[tid] = v; __syncthreads();
  for (int st = 128; st > 0; st >>= 1) {
    if (tid < st) red[tid] += red[tid + st];
    __syncthreads();
  }
  float r = red[0]; __syncthreads();
  return r;
}

__global__ void __launch_bounds__(256) k_head(const unsigned* __restrict__ hmax3u, const unsigned* __restrict__ hmin3u,
    const float* __restrict__ scale3, const float* __restrict__ shift3,
    const float* __restrict__ fc1w, const float* __restrict__ fc1b,
    const float* __restrict__ ln1g, const float* __restrict__ ln1b,
    const float* __restrict__ fc2w, const float* __restrict__ fc2b,
    const float* __restrict__ ln2g, const float* __restrict__ ln2b,
    const float* __restrict__ outw, const float* __restrict__ outb,
    float* __restrict__ out) {
  __shared__ __align__(16) float V[1024];
  __shared__ __align__(16) float H1[512];
  __shared__ __align__(16) float H2[256];
  __shared__ float red[256];
  int b = blockIdx.x, tid = threadIdx.x;
  for (int o = tid; o < 1024; o += 256) {
    float a = scale3[o];
    unsigned u = (a >= 0.f) ? hmax3u[b*1024 + o] : hmin3u[b*1024 + o];
    float h = fkeyinv(u);
    V[o] = fmaxf(fmaf(a, h, shift3[o]), 0.f);
  }
  __syncthreads();
  float h1v[2];
  #pragma unroll
  for (int ii = 0; ii < 2; ii++) {
    int o = tid + ii*256;
    const float4* wr = (const float4*)(fc1w + (size_t)o*1024);
    float s = 0.f;
    for (int c4 = 0; c4 < 256; c4++) {
      float4 w = wr[c4]; float4 vv = ((const float4*)V)[c4];
      s = fmaf(w.x, vv.x, s); s = fmaf(w.y, vv.y, s);
      s = fmaf(w.z, vv.z, s); s = fmaf(w.w, vv.w, s);
    }
    h1v[ii] = s + fc1b[o];
  }
  float s = h1v[0] + h1v[1];
  float s2 = h1v[0]*h1v[0] + h1v[1]*h1v[1];
  s = blk_reduce(s, red, tid);
  s2 = blk_reduce(s2, red, tid);
  float m = s / 512.f;
  float var = s2 / 512.f - m*m;
  float inv = 1.0f / sqrtf(var + 1e-5f);
  #pragma unroll
  for (int ii = 0; ii < 2; ii++) {
    int o = tid + ii*256;
    H1[o] = fmaxf((h1v[ii] - m)*inv*ln1g[o] + ln1b[o], 0.f);
  }
  __syncthreads();
  float h2v;
  {
    const float4* wr = (const float4*)(fc2w + (size_t)tid*512);
    float t = 0.f;
    for (int c4 = 0; c4 < 128; c4++) {
      float4 w = wr[c4]; float4 vv = ((const float4*)H1)[c4];
      t = fmaf(w.x, vv.x, t); t = fmaf(w.y, vv.y, t);
      t = fmaf(w.z, vv.z, t); t = fmaf(w.w, vv.w, t);
    }
    h2v = t + fc2b[tid];
  }
  float ss = blk_reduce(h2v, red, tid);
  float ss2 = blk_reduce(h2v*h2v, red, tid);
  float m2 = ss / 256.f;
  float var2 = ss2 / 256.f - m2*m2;
  float inv2 = 1.0f / sqrtf(var2 + 1e-5f);
  H2[tid] = fmaxf((h2v - m2)*inv2*ln2g[tid] + ln2b[tid], 0.f);
  __syncthreads();
  if (tid < 40) {
    const float4* wr = (const float4*)(outw + (size_t)tid*256);
    float t = 0.f;
    for (int c4 = 0; c4 < 64; c4++) {
      float4 w = wr[c4]; float4 vv = ((const float4*)H2)[c4];
      t = fmaf(w.x, vv.x, t); t = fmaf(w.y, vv.y, t);
      t = fmaf(w.z, vv.z, t); t = fmaf(w.w, vv.w, t);
    }
    red[tid] = t + outb[tid];
  }
  __syncthreads();
  if (tid == 0) {
    float mx = -__builtin_inff();
    for (int i2 = 0; i2 < 40; i2++) mx = fmaxf(mx, red[i2]);
    float se = 0.f;
    for (int i2 = 0; i2 < 40; i2++) se += expf(red[i2] - mx);
    float lse = mx + logf(se);
    for (int i2 = 0; i2 < 40; i2++) out[b*40 + i2] = red[i2] - lse;
  }
}

extern "C" void kernel_launch(void* const* d_in, const int* in_sizes, int n_in,
                              void* d_out, int out_size, void* d_ws, size_t ws_size,
                              hipStream_t stream) {
  (void)in_sizes; (void)n_in; (void)out_size; (void)ws_size;
  const float* x    = (const float*)d_in[0];
  const float* w1   = (const float*)d_in[1];
  const float* bn1g = (const float*)d_in[2];
  const float* bn1b = (const float*)d_in[3];
  const float* w2   = (const float*)d_in[4];
  const float* bn2g = (const float*)d_in[5];
  const float* bn2b = (const float*)d_in[6];
  const float* w3   = (const float*)d_in[7];
  const float* bn3g = (const float*)d_in[8];
  const float* bn3b = (const float*)d_in[9];
  const float* fc1w = (const float*)d_in[10];
  const float* fc1b = (const float*)d_in[11];
  const float* ln1g = (const float*)d_in[12];
  const float* ln1b = (const float*)d_in[13];
  const float* fc2w = (const float*)d_in[14];
  const float* fc2b = (const float*)d_in[15];
  const float* ln2g = (const float*)d_in[16];
  const float* ln2b = (const float*)d_in[17];
  const float* outw = (const float*)d_in[18];
  const float* outb = (const float*)d_in[19];
  float* out = (float*)d_out;

  float* ws = (float*)d_ws;
  size_t off = 0;
  float* xp1   = ws + off; off += 49152;
  int*   idx1  = (int*)(ws + off); off += 327680;
  float* hmax1 = ws + off; off += 1048576;
  float* hmin1 = ws + off; off += 1048576;
  unsigned short* feat3h = (unsigned short*)(ws + off); off += 2097152;
  float* xp2   = ws + off; off += 1048576;
  float* hmax2 = ws + off; off += 3145728;   // also pdpart (knn partials, <=160/query)
  float* hmin2 = ws + off; off += 3145728;   // also idxpart
  int*   idx2  = (int*)(ws + off); off += 327680;
  unsigned short* w2h = (unsigned short*)(ws + off); off += 24576;
  unsigned short* wt3h = (unsigned short*)(ws + off); off += 131072;
  float* x1T   = ws + off; off += 1048576;
  float* xx1   = ws + off; off += 16384;
  float* scale1 = ws + off; off += 64;
  float* shift1 = ws + off; off += 64;
  float* scale2 = ws + off; off += 192;
  float* shift2 = ws + off; off += 192;
  float* scale3 = ws + off; off += 1024;
  float* shift3 = ws + off; off += 1024;
  double* stats1sh = (double*)(ws + off);
  double* stats2sh = stats1sh + 64*64*2;
  double* stats3sh = stats2sh + 64*192*2;
  unsigned* hmax3u = (unsigned*)(stats3sh + (size_t)64*1024*2);
  unsigned* hmin3u = hmax3u + 16384;
  float* pdpart = hmax2;
  int*   idxpart = (int*)hmin2;

  size_t zero_bytes = ((size_t)64*64*2 + (size_t)64*192*2 + (size_t)64*1024*2)*8 + (size_t)16384*4;
  hipMemsetAsync(stats1sh, 0, zero_bytes, stream);
  hipMemsetAsync(hmin3u, 0xFF, (size_t)16384*4, stream);

  k_e2p1<<<64, 256, 0, stream>>>(x, xp1);
  k_knn1_part<<<512, 256, 0, stream>>>(x, pdpart, idxpart);
  k_knn_merge<8><<<64, 256, 0, stream>>>(pdpart, idxpart, idx1);
  k_transpose<<<1024, 256, 0, stream>>>(w2, w3, w2h, wt3h);
  k_conv1<<<1024, 256, 0, stream>>>(xp1, idx1, w1, hmax1, hmin1, stats1sh);
  k_bn_reduce<<<1, 64, 0, stream>>>(stats1sh, 64, 64, 327680.0, bn1g, bn1b, scale1, shift1);
  k_bn1_apply<<<4096, 256, 0, stream>>>(hmax1, hmin1, scale1, shift1, feat3h, xp2, x1T, xx1);
  k_knn2g<<<1024, 256, 0, stream>>>(x1T, xx1, pdpart, idxpart);
  k_knn_merge<4><<<64, 256, 0, stream>>>(pdpart, idxpart, idx2);
  k_conv2m<<<4096, 256, 0, stream>>>(xp2, idx2, w2h, hmax2, hmin2, stats2sh);
  k_bn_reduce<<<1, 192, 0, stream>>>(stats2sh, 64, 192, 327680.0, bn2g, bn2b, scale2, shift2);
  k_bn2_apply<<<12288, 256, 0, stream>>>(hmax2, hmin2, scale2, shift2, feat3h);
  k_conv3m<<<1024, 256, 0, stream>>>(feat3h, wt3h, stats3sh, hmax3u, hmin3u);
  k_bn_reduce<<<4, 256, 0, stream>>>(stats3sh, 64, 1024, 16384.0, bn3g, bn3b, scale3, shift3);
  k_head<<<16, 256, 0, stream>>>(hmax3u, hmin3u, scale3, shift3,
                                 fc1w, fc1b, ln1g, ln1b,
                                 fc2w, fc2b, ln2g, ln2b,
                                 outw, outb, out);
}